// Round 9
// baseline (489.565 us; speedup 1.0000x reference)
//
#include <hip/hip_runtime.h>

#define N_NODES  50000
#define N_ROWS   50048        // padded row count (multiple of 64)
#define N_EDGES  1600000
#define N_GRAPHS 2048
#define DIM      133
#define HSTR     136          // bf16 row stride for gemm-output / agg-input buffers
#define YSTR     160          // bf16 row stride for gemm-input buffers (K padded to 160)
#define EPSV     1e-5f
#define NRANGE   8
#define RSPAN    6250         // N_NODES / NRANGE
#define NSLICE   32
#define ESLICE   50000        // N_EDGES / NSLICE

typedef __attribute__((ext_vector_type(8))) short bf16x8;
typedef __attribute__((ext_vector_type(4))) float f32x4;

// ---- bf16 helpers (raw ushort; bf16 = top 16 bits of fp32) ----
__device__ __forceinline__ float blo(unsigned u) { return __uint_as_float(u << 16); }
__device__ __forceinline__ float bhi(unsigned u) { return __uint_as_float(u & 0xFFFF0000u); }
__device__ __forceinline__ unsigned short f2bf(float x) {
    unsigned v = __float_as_uint(x);
    return (unsigned short)((v + 0x7FFFu + ((v >> 16) & 1u)) >> 16);  // RNE
}
__device__ __forceinline__ unsigned packbf(float a, float b) {
    return (unsigned)f2bf(a) | ((unsigned)f2bf(b) << 16);
}

// ---------------- CSR build, atomic-free ----------------
// Grid 256 = (slice s = blockIdx>>3) x (range r = blockIdx&7); blockIdx%8==r
// pins each range's traffic to one XCD (heuristic only; correctness-independent).

// LDS histogram of slice s for range r -> deg2[s][n] (exclusive writer, no atomics).
__global__ __launch_bounds__(256) void k_count2(const int* __restrict__ col,
                                                int* __restrict__ deg2)
{
    __shared__ int hist[RSPAN];
    int r = blockIdx.x & (NRANGE - 1);
    int s = blockIdx.x >> 3;
    int lo = r * RSPAN;
    for (int i = threadIdx.x; i < RSPAN; i += 256) hist[i] = 0;
    __syncthreads();
    int e0 = s * ESLICE;
    for (int e = e0 + threadIdx.x; e < e0 + ESLICE; e += 256) {
        int c = col[e] - lo;
        if ((unsigned)c < RSPAN) atomicAdd(&hist[c], 1);
    }
    __syncthreads();
    for (int i = threadIdx.x; i < RSPAN; i += 256)
        deg2[(size_t)s * N_NODES + lo + i] = hist[i];
}

// batch is SORTED: per-graph counts via binary search (no atomics).
__global__ __launch_bounds__(256) void k_cnt(const int* __restrict__ batch,
                                             float* __restrict__ inv_cnt)
{
    int g = blockIdx.x * 256 + threadIdx.x;
    if (g >= N_GRAPHS) return;
    int a0 = 0, b0 = N_NODES;
    while (a0 < b0) { int m = (a0 + b0) >> 1; if (batch[m] < g) a0 = m + 1; else b0 = m; }
    int a1 = a0, b1 = N_NODES;
    while (a1 < b1) { int m = (a1 + b1) >> 1; if (batch[m] < g + 1) a1 = m + 1; else b1 = m; }
    inv_cnt[g] = 1.0f / (float)max(a1 - a0, 1);
}

// deg[n] = sum_s deg2[s][n]; dinv fused.
__global__ __launch_bounds__(256) void k_scanA(const int* __restrict__ deg2,
                                               int* __restrict__ deg,
                                               float* __restrict__ dinv)
{
    int n = blockIdx.x * 256 + threadIdx.x;
    if (n >= N_NODES) return;
    int d = 0;
    for (int s = 0; s < NSLICE; s++) d += deg2[(size_t)s * N_NODES + n];
    deg[n] = d;
    dinv[n] = rsqrtf((float)d + 1.0f);   // +1 self loop
}

__global__ __launch_bounds__(256) void k_scan1(const int* __restrict__ deg,
                                               int* __restrict__ offs,
                                               int* __restrict__ bsum)
{
    __shared__ int sd[256];
    int t = threadIdx.x;
    int idx = blockIdx.x * 256 + t;
    int v = (idx < N_NODES) ? deg[idx] : 0;
    sd[t] = v; __syncthreads();
    for (int o = 1; o < 256; o <<= 1) {
        int add = (t >= o) ? sd[t - o] : 0;
        __syncthreads();
        sd[t] += add;
        __syncthreads();
    }
    if (idx < N_NODES) offs[idx] = sd[t] - v;
    if (t == 255) bsum[blockIdx.x] = sd[255];
}

__global__ __launch_bounds__(256) void k_scan2(const int* __restrict__ bsum,
                                               int* __restrict__ boff, int nb)
{
    __shared__ int sd[256];
    int t = threadIdx.x;
    int v = (t < nb) ? bsum[t] : 0;
    sd[t] = v; __syncthreads();
    for (int o = 1; o < 256; o <<= 1) {
        int add = (t >= o) ? sd[t - o] : 0;
        __syncthreads();
        sd[t] += add;
        __syncthreads();
    }
    boff[t] = sd[t] - v;
}

__global__ __launch_bounds__(256) void k_scan3(int* __restrict__ offs,
                                               const int* __restrict__ boff)
{
    int idx = blockIdx.x * 256 + threadIdx.x;
    if (idx < N_NODES)       offs[idx] += boff[blockIdx.x];
    else if (idx == N_NODES) offs[N_NODES] = N_EDGES;
}

// In-place: deg2[s][n] becomes offs2[s][n] (per-(node,slice) reserved segment start).
__global__ __launch_bounds__(256) void k_scanC(const int* __restrict__ offs,
                                               int* __restrict__ deg2)
{
    int n = blockIdx.x * 256 + threadIdx.x;
    if (n >= N_NODES) return;
    int run = offs[n];
    for (int s = 0; s < NSLICE; s++) {
        int d = deg2[(size_t)s * N_NODES + n];
        deg2[(size_t)s * N_NODES + n] = run;
        run += d;
    }
}

// Fill with LDS cursors into pre-reserved disjoint segments (no global atomics).
__global__ __launch_bounds__(256) void k_fill2(const int* __restrict__ row,
                                               const int* __restrict__ col,
                                               const int* __restrict__ offs2,
                                               unsigned short* __restrict__ csr_src)
{
    __shared__ int cur[RSPAN];
    int r = blockIdx.x & (NRANGE - 1);
    int s = blockIdx.x >> 3;
    int lo = r * RSPAN;
    for (int i = threadIdx.x; i < RSPAN; i += 256)
        cur[i] = offs2[(size_t)s * N_NODES + lo + i];
    __syncthreads();
    int e0 = s * ESLICE;
    for (int e = e0 + threadIdx.x; e < e0 + ESLICE; e += 256) {
        int c = col[e] - lo;
        if ((unsigned)c < RSPAN) {
            int p = atomicAdd(&cur[c], 1);
            csr_src[p] = (unsigned short)row[e];
        }
    }
}

// ---- pack W (fp32 [133][133], W[k][n]) into MFMA B-fragment layout ----
__global__ __launch_bounds__(256) void k_w2bf(const float* __restrict__ W,
                                              unsigned short* __restrict__ Wbf)
{
    int idx = blockIdx.x * 256 + threadIdx.x;          // 9*5*64*8 = 23040
    if (idx >= 23040) return;
    int j    = idx & 7;
    int lane = (idx >> 3) & 63;
    int kc   = (idx >> 9) % 5;
    int t    = idx / (8 * 64 * 5);
    int k = kc * 32 + (lane >> 4) * 8 + j;
    int n = t * 16 + (lane & 15);
    float v = (k < DIM && n < DIM) ? W[k * DIM + n] : 0.f;
    Wbf[idx] = f2bf(v);
}

// ---- convert x fp32 [N][133] -> bf16 [N][160] with zero K-padding ----
__global__ __launch_bounds__(256) void k_x2bf(const float* __restrict__ x,
                                              unsigned* __restrict__ Abf) // uint = 2 bf16
{
    int idx = blockIdx.x * 256 + threadIdx.x;          // N_NODES * 80
    if (idx >= N_NODES * 80) return;
    int r  = idx / 80;
    int c2 = (idx - r * 80) * 2;
    float a = (c2     < DIM) ? x[(size_t)r * DIM + c2]     : 0.f;
    float b = (c2 + 1 < DIM) ? x[(size_t)r * DIM + c2 + 1] : 0.f;
    Abf[idx] = packbf(a, b);
}

// ---------------- MFMA GEMM: H[M][HSTR](bf16) = A[.][YSTR](bf16) @ W ----------------
__global__ __launch_bounds__(256) void k_gemm_mfma(const unsigned short* __restrict__ A,
                                                   const unsigned short* __restrict__ Wbf,
                                                   unsigned short* __restrict__ H, int M)
{
    int wave = threadIdx.x >> 6, lane = threadIdx.x & 63;
    int quad = lane >> 4, l16 = lane & 15;
    int m = blockIdx.x * 64 + wave * 16 + l16;

    const bf16x8* Arow = (const bf16x8*)(A + (size_t)m * YSTR);
    const bf16x8* Bq   = (const bf16x8*)Wbf;

    f32x4 acc[9] = {};
#pragma unroll
    for (int kc = 0; kc < 5; kc++) {
        bf16x8 af = Arow[kc * 4 + quad];
#pragma unroll
        for (int t = 0; t < 9; t++) {
            bf16x8 bfr = Bq[(t * 5 + kc) * 64 + lane];
            acc[t] = __builtin_amdgcn_mfma_f32_16x16x32_bf16(af, bfr, acc[t], 0, 0, 0);
        }
    }

    int gr0 = blockIdx.x * 64 + wave * 16 + quad * 4;
#pragma unroll
    for (int t = 0; t < 9; t++) {
        int c = t * 16 + l16;
#pragma unroll
        for (int reg = 0; reg < 4; reg++) {
            int gr = gr0 + reg;
            if (gr < M && c < HSTR) {
                float v = (c < DIM) ? acc[t][reg] : 0.f;
                H[(size_t)gr * HSTR + c] = f2bf(v);
            }
        }
    }
}

// ---------------- fused aggregate + bias + ReLU + BN (+ optional mean-pool) ----------------
// 8x-unrolled gather loop (R7 post-mortem: x16/uint2 variant regressed via VGPR/occupancy).

template <bool FINAL>
__global__ __launch_bounds__(256) void k_agg(const unsigned short* __restrict__ h,
                                             const int* __restrict__ offs,
                                             const unsigned short* __restrict__ csr_src,
                                             const float* __restrict__ dinv,
                                             const float* __restrict__ bias,
                                             const float* __restrict__ gam,
                                             const float* __restrict__ bet,
                                             const float* __restrict__ rmean,
                                             const float* __restrict__ rvar,
                                             unsigned short* __restrict__ y,
                                             const int* __restrict__ batch,
                                             const float* __restrict__ inv_cnt,
                                             float* __restrict__ outp)
{
    int node = blockIdx.x * 4 + (threadIdx.x >> 6);
    if (node >= N_NODES) return;
    int lane = threadIdx.x & 63;
    int l2 = lane & 3;

    float di = dinv[node];
    const unsigned* hrow = (const unsigned*)(h + (size_t)node * HSTR);
    unsigned p0 = hrow[lane];        // cols 2*lane, 2*lane+1
    unsigned p1 = hrow[64 + l2];     // cols 128+2*l2 (dup for lanes>=4, discarded)
    float2 a0; a0.x = di * blo(p0); a0.y = di * bhi(p0);   // self-loop term
    float2 a1; a1.x = di * blo(p1); a1.y = di * bhi(p1);

    int s0 = offs[node], s1 = offs[node + 1];
    for (int k0 = s0; k0 < s1; k0 += 64) {
        int nk = min(64, s1 - k0);
        int src = 0; float w = 0.f;
        if (lane < nk) {
            src = csr_src[k0 + lane];
            w   = dinv[src];          // L2-resident 200 KB table
        }
        int j = 0;
        for (; j + 8 <= nk; j += 8) {
            int   ss[8];
            float wv[8];
#pragma unroll
            for (int u = 0; u < 8; u++) {
                ss[u] = __builtin_amdgcn_readfirstlane(__shfl(src, j + u));
                wv[u] = __shfl(w, j + u);
            }
            unsigned q0[8], q1[8];
#pragma unroll
            for (int u = 0; u < 8; u++) {
                const unsigned* r = (const unsigned*)(h + (size_t)ss[u] * HSTR);
                q0[u] = r[lane];
                q1[u] = r[64 + l2];
            }
#pragma unroll
            for (int u = 0; u < 8; u++) {
                a0.x += wv[u] * blo(q0[u]); a0.y += wv[u] * bhi(q0[u]);
                a1.x += wv[u] * blo(q1[u]); a1.y += wv[u] * bhi(q1[u]);
            }
        }
        for (; j < nk; j++) {
            int   s  = __builtin_amdgcn_readfirstlane(__shfl(src, j));
            float ww = __shfl(w, j);
            const unsigned* hr = (const unsigned*)(h + (size_t)s * HSTR);
            unsigned q0 = hr[lane];
            unsigned q1 = hr[64 + l2];
            a0.x += ww * blo(q0); a0.y += ww * bhi(q0);
            a1.x += ww * blo(q1); a1.y += ww * bhi(q1);
        }
    }

    float ic = 0.f; int bg = 0;
    if (FINAL) { bg = batch[node]; ic = inv_cnt[bg]; }

    // main pair: cols 2*lane, 2*lane+1 (both < 128 < DIM)
    {
        int c = 2 * lane;
        float va = di * a0.x + bias[c];
        va = fmaxf(va, 0.f);
        va = (va - rmean[c]) * (gam[c] * rsqrtf(rvar[c] + EPSV)) + bet[c];
        int c1 = c + 1;
        float vb = di * a0.y + bias[c1];
        vb = fmaxf(vb, 0.f);
        vb = (vb - rmean[c1]) * (gam[c1] * rsqrtf(rvar[c1] + EPSV)) + bet[c1];
        if (FINAL) {
            atomicAdd(&outp[(size_t)bg * DIM + c],  va * ic);
            atomicAdd(&outp[(size_t)bg * DIM + c1], vb * ic);
        } else {
            ((unsigned*)(y + (size_t)node * YSTR))[lane] = packbf(va, vb);
        }
    }
    // tail: cols 128..159. lanes 0-3 compute cols 128+2*l2 (masked >=133); lanes 4-15 pad zeros.
    if (lane < 16) {
        float va = 0.f, vb = 0.f;
        if (lane < 4) {
            int c = 128 + 2 * l2;
            if (c < DIM) {
                va = di * a1.x + bias[c];
                va = fmaxf(va, 0.f);
                va = (va - rmean[c]) * (gam[c] * rsqrtf(rvar[c] + EPSV)) + bet[c];
            }
            int c1 = c + 1;
            if (c1 < DIM) {
                vb = di * a1.y + bias[c1];
                vb = fmaxf(vb, 0.f);
                vb = (vb - rmean[c1]) * (gam[c1] * rsqrtf(rvar[c1] + EPSV)) + bet[c1];
            }
            if (FINAL) {
                if (c  < DIM) atomicAdd(&outp[(size_t)bg * DIM + c],  va * ic);
                if (c1 < DIM) atomicAdd(&outp[(size_t)bg * DIM + c1], vb * ic);
            }
        }
        if (!FINAL)
            ((unsigned*)(y + (size_t)node * YSTR))[64 + lane] = packbf(va, vb);
    }
}

// ---------------- launch ----------------

extern "C" void kernel_launch(void* const* d_in, const int* in_sizes, int n_in,
                              void* d_out, int out_size, void* d_ws, size_t ws_size,
                              hipStream_t stream)
{
    const float* x   = (const float*)d_in[0];
    const int*   ei  = (const int*)d_in[1];
    const int*   bat = (const int*)d_in[2];
    const float* W1  = (const float*)d_in[3];
    const float* b1  = (const float*)d_in[4];
    const float* W2  = (const float*)d_in[5];
    const float* b2  = (const float*)d_in[6];
    const float* g1  = (const float*)d_in[7];
    const float* be1 = (const float*)d_in[8];
    const float* rm1 = (const float*)d_in[9];
    const float* rv1 = (const float*)d_in[10];
    const float* g2  = (const float*)d_in[11];
    const float* be2 = (const float*)d_in[12];
    const float* rm2 = (const float*)d_in[13];
    const float* rv2 = (const float*)d_in[14];
    float* outp = (float*)d_out;
    char* ws = (char*)d_ws;

    int*   deg     = (int*)  (ws + 0);         // 200000 B
    int*   offs    = (int*)  (ws + 200000);    // 200016 B (N+1 ints)
    float* dinv    = (float*)(ws + 400016);    // 200000 B
    float* inv_cnt = (float*)(ws + 600016);    //   8192 B
    int*   bsum    = (int*)  (ws + 608208);    //   1024 B
    int*   boff    = (int*)  (ws + 609232);    //   1024 B
    unsigned short* csr_src = (unsigned short*)(ws + 610256);   // 3.2 MB
    unsigned short* Wbf1 = (unsigned short*)(ws + 3810256);     // 46080 B
    unsigned short* Wbf2 = (unsigned short*)(ws + 3856336);     // 46080 B
    unsigned short* Abf  = (unsigned short*)(ws + 3902416);     // 16015360 B (50048 x 160)
    unsigned short* Hb   = (unsigned short*)(ws + 19917776);    // 13613056 B (50048 x 136)
    unsigned short* Y1   = (unsigned short*)(ws + 33530832);    // 16015360 B (50048 x 160)
    // deg2/offs2 (32 x 50000 ints = 6.4 MB) aliases Y1: lifetime ends (k_fill2)
    // before Y1 is first written (k_agg<false>).
    int* deg2 = (int*)(ws + 33530832);

    hipMemsetAsync(d_out, 0, (size_t)out_size * 4, stream);

    const int* row = ei;
    const int* col = ei + N_EDGES;

    int nbl = (N_NODES + 255) / 256;

    k_count2<<<dim3(NSLICE * NRANGE), dim3(256), 0, stream>>>(col, deg2);
    k_cnt   <<<dim3(N_GRAPHS / 256),  dim3(256), 0, stream>>>(bat, inv_cnt);
    k_scanA <<<dim3(nbl), dim3(256), 0, stream>>>(deg2, deg, dinv);
    k_scan1 <<<dim3(nbl), dim3(256), 0, stream>>>(deg, offs, bsum);
    k_scan2 <<<dim3(1),   dim3(256), 0, stream>>>(bsum, boff, nbl);
    k_scan3 <<<dim3(nbl), dim3(256), 0, stream>>>(offs, boff);
    k_scanC <<<dim3(nbl), dim3(256), 0, stream>>>(offs, deg2);
    k_fill2 <<<dim3(NSLICE * NRANGE), dim3(256), 0, stream>>>(row, col, deg2, csr_src);

    k_w2bf<<<dim3(90), dim3(256), 0, stream>>>(W1, Wbf1);
    k_w2bf<<<dim3(90), dim3(256), 0, stream>>>(W2, Wbf2);
    k_x2bf<<<dim3((N_NODES * 80 + 255) / 256), dim3(256), 0, stream>>>(x, (unsigned*)Abf);

    int gbl = N_ROWS / 64;   // 782
    k_gemm_mfma<<<dim3(gbl), dim3(256), 0, stream>>>(Abf, Wbf1, Hb, N_NODES);
    k_agg<false><<<dim3(N_NODES / 4), dim3(256), 0, stream>>>(Hb, offs, csr_src, dinv,
                                                              b1, g1, be1, rm1, rv1,
                                                              Y1, nullptr, nullptr, nullptr);
    k_gemm_mfma<<<dim3(gbl), dim3(256), 0, stream>>>(Y1, Wbf2, Hb, N_NODES);
    k_agg<true><<<dim3(N_NODES / 4), dim3(256), 0, stream>>>(Hb, offs, csr_src, dinv,
                                                             b2, g2, be2, rm2, rv2,
                                                             nullptr, bat, inv_cnt, outp);
}

// Round 10
// 422.696 us; speedup vs baseline: 1.1582x; 1.1582x over previous
//
#include <hip/hip_runtime.h>

#define N_NODES  50000
#define N_ROWS   50048        // padded row count (multiple of 64)
#define N_EDGES  1600000
#define N_GRAPHS 2048
#define DIM      133
#define HSTR     136          // bf16 row stride for gemm-output / agg-input buffers
#define YSTR     160          // bf16 row stride for gemm-input buffers (K padded to 160)
#define EPSV     1e-5f
#define NRANGE   16
#define RSPAN    3125         // N_NODES / NRANGE
#define NSLICE   64
#define ESLICE   25000        // N_EDGES / NSLICE

typedef __attribute__((ext_vector_type(8))) short bf16x8;
typedef __attribute__((ext_vector_type(4))) float f32x4;

// ---- bf16 helpers (raw ushort; bf16 = top 16 bits of fp32) ----
__device__ __forceinline__ float blo(unsigned u) { return __uint_as_float(u << 16); }
__device__ __forceinline__ float bhi(unsigned u) { return __uint_as_float(u & 0xFFFF0000u); }
__device__ __forceinline__ unsigned short f2bf(float x) {
    unsigned v = __float_as_uint(x);
    return (unsigned short)((v + 0x7FFFu + ((v >> 16) & 1u)) >> 16);  // RNE
}
__device__ __forceinline__ unsigned packbf(float a, float b) {
    return (unsigned)f2bf(a) | ((unsigned)f2bf(b) << 16);
}

// ---------------- CSR build, atomic-free (global) ----------------
// Grid 1024 = (slice s = blockIdx>>4) x (range r = blockIdx&15).
// R9 post-mortem: 256-block version was latency-bound at 11% occupancy;
// 1024 blocks / 12.5 KB LDS gives ~4 blocks/CU.

// LDS histogram of slice s for range r -> deg2[s][n] (exclusive writer).
__global__ __launch_bounds__(256) void k_count2(const int* __restrict__ col,
                                                int* __restrict__ deg2)
{
    __shared__ int hist[RSPAN];
    int r = blockIdx.x & (NRANGE - 1);
    int s = blockIdx.x >> 4;
    int lo = r * RSPAN;
    for (int i = threadIdx.x; i < RSPAN; i += 256) hist[i] = 0;
    __syncthreads();
    int e0 = s * ESLICE;
    for (int e = e0 + threadIdx.x; e < e0 + ESLICE; e += 256) {
        int c = col[e] - lo;
        if ((unsigned)c < RSPAN) atomicAdd(&hist[c], 1);
    }
    __syncthreads();
    for (int i = threadIdx.x; i < RSPAN; i += 256)
        deg2[(size_t)s * N_NODES + lo + i] = hist[i];
}

// batch is SORTED: per-graph counts via binary search (no atomics).
__global__ __launch_bounds__(256) void k_cnt(const int* __restrict__ batch,
                                             float* __restrict__ inv_cnt)
{
    int g = blockIdx.x * 256 + threadIdx.x;
    if (g >= N_GRAPHS) return;
    int a0 = 0, b0 = N_NODES;
    while (a0 < b0) { int m = (a0 + b0) >> 1; if (batch[m] < g) a0 = m + 1; else b0 = m; }
    int a1 = a0, b1 = N_NODES;
    while (a1 < b1) { int m = (a1 + b1) >> 1; if (batch[m] < g + 1) a1 = m + 1; else b1 = m; }
    inv_cnt[g] = 1.0f / (float)max(a1 - a0, 1);
}

// deg[n] = sum_s deg2[s][n]; dinv fused.
__global__ __launch_bounds__(256) void k_scanA(const int* __restrict__ deg2,
                                               int* __restrict__ deg,
                                               float* __restrict__ dinv)
{
    int n = blockIdx.x * 256 + threadIdx.x;
    if (n >= N_NODES) return;
    int d = 0;
    for (int s = 0; s < NSLICE; s++) d += deg2[(size_t)s * N_NODES + n];
    deg[n] = d;
    dinv[n] = rsqrtf((float)d + 1.0f);   // +1 self loop
}

__global__ __launch_bounds__(256) void k_scan1(const int* __restrict__ deg,
                                               int* __restrict__ offs,
                                               int* __restrict__ bsum)
{
    __shared__ int sd[256];
    int t = threadIdx.x;
    int idx = blockIdx.x * 256 + t;
    int v = (idx < N_NODES) ? deg[idx] : 0;
    sd[t] = v; __syncthreads();
    for (int o = 1; o < 256; o <<= 1) {
        int add = (t >= o) ? sd[t - o] : 0;
        __syncthreads();
        sd[t] += add;
        __syncthreads();
    }
    if (idx < N_NODES) offs[idx] = sd[t] - v;
    if (t == 255) bsum[blockIdx.x] = sd[255];
}

__global__ __launch_bounds__(256) void k_scan2(const int* __restrict__ bsum,
                                               int* __restrict__ boff, int nb)
{
    __shared__ int sd[256];
    int t = threadIdx.x;
    int v = (t < nb) ? bsum[t] : 0;
    sd[t] = v; __syncthreads();
    for (int o = 1; o < 256; o <<= 1) {
        int add = (t >= o) ? sd[t - o] : 0;
        __syncthreads();
        sd[t] += add;
        __syncthreads();
    }
    boff[t] = sd[t] - v;
}

__global__ __launch_bounds__(256) void k_scan3(int* __restrict__ offs,
                                               const int* __restrict__ boff)
{
    int idx = blockIdx.x * 256 + threadIdx.x;
    if (idx < N_NODES)       offs[idx] += boff[blockIdx.x];
    else if (idx == N_NODES) offs[N_NODES] = N_EDGES;
}

// In-place: deg2[s][n] becomes offs2[s][n] (per-(node,slice) reserved segment start).
__global__ __launch_bounds__(256) void k_scanC(const int* __restrict__ offs,
                                               int* __restrict__ deg2)
{
    int n = blockIdx.x * 256 + threadIdx.x;
    if (n >= N_NODES) return;
    int run = offs[n];
    for (int s = 0; s < NSLICE; s++) {
        int d = deg2[(size_t)s * N_NODES + n];
        deg2[(size_t)s * N_NODES + n] = run;
        run += d;
    }
}

// Fill with LDS cursors into pre-reserved disjoint segments (no global atomics).
__global__ __launch_bounds__(256) void k_fill2(const int* __restrict__ row,
                                               const int* __restrict__ col,
                                               const int* __restrict__ offs2,
                                               unsigned short* __restrict__ csr_src)
{
    __shared__ int cur[RSPAN];
    int r = blockIdx.x & (NRANGE - 1);
    int s = blockIdx.x >> 4;
    int lo = r * RSPAN;
    for (int i = threadIdx.x; i < RSPAN; i += 256)
        cur[i] = offs2[(size_t)s * N_NODES + lo + i];
    __syncthreads();
    int e0 = s * ESLICE;
    for (int e = e0 + threadIdx.x; e < e0 + ESLICE; e += 256) {
        int c = col[e] - lo;
        if ((unsigned)c < RSPAN) {
            int p = atomicAdd(&cur[c], 1);
            csr_src[p] = (unsigned short)row[e];
        }
    }
}

// ---- pack W (fp32 [133][133], W[k][n]) into MFMA B-fragment layout ----
__global__ __launch_bounds__(256) void k_w2bf(const float* __restrict__ W,
                                              unsigned short* __restrict__ Wbf)
{
    int idx = blockIdx.x * 256 + threadIdx.x;          // 9*5*64*8 = 23040
    if (idx >= 23040) return;
    int j    = idx & 7;
    int lane = (idx >> 3) & 63;
    int kc   = (idx >> 9) % 5;
    int t    = idx / (8 * 64 * 5);
    int k = kc * 32 + (lane >> 4) * 8 + j;
    int n = t * 16 + (lane & 15);
    float v = (k < DIM && n < DIM) ? W[k * DIM + n] : 0.f;
    Wbf[idx] = f2bf(v);
}

// ---- convert x fp32 [N][133] -> bf16 [N][160] with zero K-padding ----
__global__ __launch_bounds__(256) void k_x2bf(const float* __restrict__ x,
                                              unsigned* __restrict__ Abf) // uint = 2 bf16
{
    int idx = blockIdx.x * 256 + threadIdx.x;          // N_NODES * 80
    if (idx >= N_NODES * 80) return;
    int r  = idx / 80;
    int c2 = (idx - r * 80) * 2;
    float a = (c2     < DIM) ? x[(size_t)r * DIM + c2]     : 0.f;
    float b = (c2 + 1 < DIM) ? x[(size_t)r * DIM + c2 + 1] : 0.f;
    Abf[idx] = packbf(a, b);
}

// ---------------- MFMA GEMM: H[M][HSTR](bf16) = A[.][YSTR](bf16) @ W ----------------
__global__ __launch_bounds__(256) void k_gemm_mfma(const unsigned short* __restrict__ A,
                                                   const unsigned short* __restrict__ Wbf,
                                                   unsigned short* __restrict__ H, int M)
{
    int wave = threadIdx.x >> 6, lane = threadIdx.x & 63;
    int quad = lane >> 4, l16 = lane & 15;
    int m = blockIdx.x * 64 + wave * 16 + l16;

    const bf16x8* Arow = (const bf16x8*)(A + (size_t)m * YSTR);
    const bf16x8* Bq   = (const bf16x8*)Wbf;

    f32x4 acc[9] = {};
#pragma unroll
    for (int kc = 0; kc < 5; kc++) {
        bf16x8 af = Arow[kc * 4 + quad];
#pragma unroll
        for (int t = 0; t < 9; t++) {
            bf16x8 bfr = Bq[(t * 5 + kc) * 64 + lane];
            acc[t] = __builtin_amdgcn_mfma_f32_16x16x32_bf16(af, bfr, acc[t], 0, 0, 0);
        }
    }

    int gr0 = blockIdx.x * 64 + wave * 16 + quad * 4;
#pragma unroll
    for (int t = 0; t < 9; t++) {
        int c = t * 16 + l16;
#pragma unroll
        for (int reg = 0; reg < 4; reg++) {
            int gr = gr0 + reg;
            if (gr < M && c < HSTR) {
                float v = (c < DIM) ? acc[t][reg] : 0.f;
                H[(size_t)gr * HSTR + c] = f2bf(v);
            }
        }
    }
}

// ---------------- fused aggregate + bias + ReLU + BN (+ optional mean-pool) ----------------
// 8x-unrolled gather loop (R7 post-mortem: x16/uint2 variant regressed via VGPR/occupancy).

template <bool FINAL>
__global__ __launch_bounds__(256) void k_agg(const unsigned short* __restrict__ h,
                                             const int* __restrict__ offs,
                                             const unsigned short* __restrict__ csr_src,
                                             const float* __restrict__ dinv,
                                             const float* __restrict__ bias,
                                             const float* __restrict__ gam,
                                             const float* __restrict__ bet,
                                             const float* __restrict__ rmean,
                                             const float* __restrict__ rvar,
                                             unsigned short* __restrict__ y,
                                             const int* __restrict__ batch,
                                             const float* __restrict__ inv_cnt,
                                             float* __restrict__ outp)
{
    int node = blockIdx.x * 4 + (threadIdx.x >> 6);
    if (node >= N_NODES) return;
    int lane = threadIdx.x & 63;
    int l2 = lane & 3;

    float di = dinv[node];
    const unsigned* hrow = (const unsigned*)(h + (size_t)node * HSTR);
    unsigned p0 = hrow[lane];        // cols 2*lane, 2*lane+1
    unsigned p1 = hrow[64 + l2];     // cols 128+2*l2 (dup for lanes>=4, discarded)
    float2 a0; a0.x = di * blo(p0); a0.y = di * bhi(p0);   // self-loop term
    float2 a1; a1.x = di * blo(p1); a1.y = di * bhi(p1);

    int s0 = offs[node], s1 = offs[node + 1];
    for (int k0 = s0; k0 < s1; k0 += 64) {
        int nk = min(64, s1 - k0);
        int src = 0; float w = 0.f;
        if (lane < nk) {
            src = csr_src[k0 + lane];
            w   = dinv[src];          // L2-resident 200 KB table
        }
        int j = 0;
        for (; j + 8 <= nk; j += 8) {
            int   ss[8];
            float wv[8];
#pragma unroll
            for (int u = 0; u < 8; u++) {
                ss[u] = __builtin_amdgcn_readfirstlane(__shfl(src, j + u));
                wv[u] = __shfl(w, j + u);
            }
            unsigned q0[8], q1[8];
#pragma unroll
            for (int u = 0; u < 8; u++) {
                const unsigned* r = (const unsigned*)(h + (size_t)ss[u] * HSTR);
                q0[u] = r[lane];
                q1[u] = r[64 + l2];
            }
#pragma unroll
            for (int u = 0; u < 8; u++) {
                a0.x += wv[u] * blo(q0[u]); a0.y += wv[u] * bhi(q0[u]);
                a1.x += wv[u] * blo(q1[u]); a1.y += wv[u] * bhi(q1[u]);
            }
        }
        for (; j < nk; j++) {
            int   s  = __builtin_amdgcn_readfirstlane(__shfl(src, j));
            float ww = __shfl(w, j);
            const unsigned* hr = (const unsigned*)(h + (size_t)s * HSTR);
            unsigned q0 = hr[lane];
            unsigned q1 = hr[64 + l2];
            a0.x += ww * blo(q0); a0.y += ww * bhi(q0);
            a1.x += ww * blo(q1); a1.y += ww * bhi(q1);
        }
    }

    float ic = 0.f; int bg = 0;
    if (FINAL) { bg = batch[node]; ic = inv_cnt[bg]; }

    // main pair: cols 2*lane, 2*lane+1 (both < 128 < DIM)
    {
        int c = 2 * lane;
        float va = di * a0.x + bias[c];
        va = fmaxf(va, 0.f);
        va = (va - rmean[c]) * (gam[c] * rsqrtf(rvar[c] + EPSV)) + bet[c];
        int c1 = c + 1;
        float vb = di * a0.y + bias[c1];
        vb = fmaxf(vb, 0.f);
        vb = (vb - rmean[c1]) * (gam[c1] * rsqrtf(rvar[c1] + EPSV)) + bet[c1];
        if (FINAL) {
            atomicAdd(&outp[(size_t)bg * DIM + c],  va * ic);
            atomicAdd(&outp[(size_t)bg * DIM + c1], vb * ic);
        } else {
            ((unsigned*)(y + (size_t)node * YSTR))[lane] = packbf(va, vb);
        }
    }
    // tail: cols 128..159. lanes 0-3 compute cols 128+2*l2 (masked >=133); lanes 4-15 pad zeros.
    if (lane < 16) {
        float va = 0.f, vb = 0.f;
        if (lane < 4) {
            int c = 128 + 2 * l2;
            if (c < DIM) {
                va = di * a1.x + bias[c];
                va = fmaxf(va, 0.f);
                va = (va - rmean[c]) * (gam[c] * rsqrtf(rvar[c] + EPSV)) + bet[c];
            }
            int c1 = c + 1;
            if (c1 < DIM) {
                vb = di * a1.y + bias[c1];
                vb = fmaxf(vb, 0.f);
                vb = (vb - rmean[c1]) * (gam[c1] * rsqrtf(rvar[c1] + EPSV)) + bet[c1];
            }
            if (FINAL) {
                if (c  < DIM) atomicAdd(&outp[(size_t)bg * DIM + c],  va * ic);
                if (c1 < DIM) atomicAdd(&outp[(size_t)bg * DIM + c1], vb * ic);
            }
        }
        if (!FINAL)
            ((unsigned*)(y + (size_t)node * YSTR))[64 + lane] = packbf(va, vb);
    }
}

// ---------------- launch ----------------

extern "C" void kernel_launch(void* const* d_in, const int* in_sizes, int n_in,
                              void* d_out, int out_size, void* d_ws, size_t ws_size,
                              hipStream_t stream)
{
    const float* x   = (const float*)d_in[0];
    const int*   ei  = (const int*)d_in[1];
    const int*   bat = (const int*)d_in[2];
    const float* W1  = (const float*)d_in[3];
    const float* b1  = (const float*)d_in[4];
    const float* W2  = (const float*)d_in[5];
    const float* b2  = (const float*)d_in[6];
    const float* g1  = (const float*)d_in[7];
    const float* be1 = (const float*)d_in[8];
    const float* rm1 = (const float*)d_in[9];
    const float* rv1 = (const float*)d_in[10];
    const float* g2  = (const float*)d_in[11];
    const float* be2 = (const float*)d_in[12];
    const float* rm2 = (const float*)d_in[13];
    const float* rv2 = (const float*)d_in[14];
    float* outp = (float*)d_out;
    char* ws = (char*)d_ws;

    int*   deg     = (int*)  (ws + 0);         // 200000 B
    int*   offs    = (int*)  (ws + 200000);    // 200016 B (N+1 ints)
    float* dinv    = (float*)(ws + 400016);    // 200000 B
    float* inv_cnt = (float*)(ws + 600016);    //   8192 B
    int*   bsum    = (int*)  (ws + 608208);    //   1024 B
    int*   boff    = (int*)  (ws + 609232);    //   1024 B
    unsigned short* csr_src = (unsigned short*)(ws + 610256);   // 3.2 MB
    unsigned short* Wbf1 = (unsigned short*)(ws + 3810256);     // 46080 B
    unsigned short* Wbf2 = (unsigned short*)(ws + 3856336);     // 46080 B
    unsigned short* Abf  = (unsigned short*)(ws + 3902416);     // 16015360 B (50048 x 160)
    unsigned short* Hb   = (unsigned short*)(ws + 19917776);    // 13613056 B (50048 x 136)
    unsigned short* Y1   = (unsigned short*)(ws + 33530832);    // 16015360 B (50048 x 160)
    // deg2/offs2 (64 x 50000 ints = 12.8 MB) aliases Y1: lifetime ends (k_fill2)
    // before Y1 is first written (k_agg<false>).
    int* deg2 = (int*)(ws + 33530832);

    hipMemsetAsync(d_out, 0, (size_t)out_size * 4, stream);

    const int* row = ei;
    const int* col = ei + N_EDGES;

    int nbl = (N_NODES + 255) / 256;

    k_count2<<<dim3(NSLICE * NRANGE), dim3(256), 0, stream>>>(col, deg2);
    k_cnt   <<<dim3(N_GRAPHS / 256),  dim3(256), 0, stream>>>(bat, inv_cnt);
    k_scanA <<<dim3(nbl), dim3(256), 0, stream>>>(deg2, deg, dinv);
    k_scan1 <<<dim3(nbl), dim3(256), 0, stream>>>(deg, offs, bsum);
    k_scan2 <<<dim3(1),   dim3(256), 0, stream>>>(bsum, boff, nbl);
    k_scan3 <<<dim3(nbl), dim3(256), 0, stream>>>(offs, boff);
    k_scanC <<<dim3(nbl), dim3(256), 0, stream>>>(offs, deg2);
    k_fill2 <<<dim3(NSLICE * NRANGE), dim3(256), 0, stream>>>(row, col, deg2, csr_src);

    k_w2bf<<<dim3(90), dim3(256), 0, stream>>>(W1, Wbf1);
    k_w2bf<<<dim3(90), dim3(256), 0, stream>>>(W2, Wbf2);
    k_x2bf<<<dim3((N_NODES * 80 + 255) / 256), dim3(256), 0, stream>>>(x, (unsigned*)Abf);

    int gbl = N_ROWS / 64;   // 782
    k_gemm_mfma<<<dim3(gbl), dim3(256), 0, stream>>>(Abf, Wbf1, Hb, N_NODES);
    k_agg<false><<<dim3(N_NODES / 4), dim3(256), 0, stream>>>(Hb, offs, csr_src, dinv,
                                                              b1, g1, be1, rm1, rv1,
                                                              Y1, nullptr, nullptr, nullptr);
    k_gemm_mfma<<<dim3(gbl), dim3(256), 0, stream>>>(Y1, Wbf2, Hb, N_NODES);
    k_agg<true><<<dim3(N_NODES / 4), dim3(256), 0, stream>>>(Hb, offs, csr_src, dinv,
                                                             b2, g2, be2, rm2, rv2,
                                                             nullptr, bat, inv_cnt, outp);
}

// Round 11
// 381.040 us; speedup vs baseline: 1.2848x; 1.1093x over previous
//
#include <hip/hip_runtime.h>

#define N_NODES  50000
#define N_ROWS   50048        // padded row count (multiple of 64)
#define N_EDGES  1600000
#define N_GRAPHS 2048
#define DIM      133
#define HSTR     136          // bf16 row stride for gemm-output / agg-input buffers
#define YSTR     160          // bf16 row stride for gemm-input buffers (K padded to 160)
#define EPSV     1e-5f
#define NRANGE   16
#define RSPAN    3125         // N_NODES / NRANGE
#define NSLICE   128
#define ESLICE   12500        // N_EDGES / NSLICE

typedef __attribute__((ext_vector_type(8))) short bf16x8;
typedef __attribute__((ext_vector_type(4))) float f32x4;

// ---- bf16 helpers (raw ushort; bf16 = top 16 bits of fp32) ----
__device__ __forceinline__ float blo(unsigned u) { return __uint_as_float(u << 16); }
__device__ __forceinline__ float bhi(unsigned u) { return __uint_as_float(u & 0xFFFF0000u); }
__device__ __forceinline__ unsigned short f2bf(float x) {
    unsigned v = __float_as_uint(x);
    return (unsigned short)((v + 0x7FFFu + ((v >> 16) & 1u)) >> 16);  // RNE
}
__device__ __forceinline__ unsigned packbf(float a, float b) {
    return (unsigned)f2bf(a) | ((unsigned)f2bf(b) << 16);
}

// ---------------- CSR build, atomic-free (global) ----------------
// Grid 2048 = (slice s = blockIdx>>4) x (range r = blockIdx&15); 8 blocks/CU.

// LDS histogram of slice s for range r -> deg2[s][n] (exclusive writer).
__global__ __launch_bounds__(256) void k_count2(const int* __restrict__ col,
                                                int* __restrict__ deg2)
{
    __shared__ int hist[RSPAN];
    int r = blockIdx.x & (NRANGE - 1);
    int s = blockIdx.x >> 4;
    int lo = r * RSPAN;
    for (int i = threadIdx.x; i < RSPAN; i += 256) hist[i] = 0;
    __syncthreads();
    int e0 = s * ESLICE;
    for (int e = e0 + threadIdx.x; e < e0 + ESLICE; e += 256) {
        int c = col[e] - lo;
        if ((unsigned)c < RSPAN) atomicAdd(&hist[c], 1);
    }
    __syncthreads();
    for (int i = threadIdx.x; i < RSPAN; i += 256)
        deg2[(size_t)s * N_NODES + lo + i] = hist[i];
}

// Combined small setup: pack W1,W2 into MFMA B-layout + per-graph inv counts.
// Wbf[((t*5 + kc)*64 + lane)*8 + j] = bf16(W[kc*32+(lane>>4)*8+j][t*16+(lane&15)])
__device__ __forceinline__ void w2bf_one(const float* __restrict__ W,
                                         unsigned short* __restrict__ Wbf, int idx)
{
    int j    = idx & 7;
    int lane = (idx >> 3) & 63;
    int kc   = (idx >> 9) % 5;
    int t    = idx / (8 * 64 * 5);
    int k = kc * 32 + (lane >> 4) * 8 + j;
    int n = t * 16 + (lane & 15);
    float v = (k < DIM && n < DIM) ? W[k * DIM + n] : 0.f;
    Wbf[idx] = f2bf(v);
}

__global__ __launch_bounds__(256) void k_setup(const float* __restrict__ W1,
                                               const float* __restrict__ W2,
                                               unsigned short* __restrict__ Wbf1,
                                               unsigned short* __restrict__ Wbf2,
                                               const int* __restrict__ batch,
                                               float* __restrict__ inv_cnt)
{
    int tid = blockIdx.x * 256 + threadIdx.x;
    if (tid < 23040) {
        w2bf_one(W1, Wbf1, tid);
    } else if (tid < 46080) {
        w2bf_one(W2, Wbf2, tid - 23040);
    } else if (tid < 46080 + N_GRAPHS) {
        int g = tid - 46080;                    // batch SORTED: binary search
        int a0 = 0, b0 = N_NODES;
        while (a0 < b0) { int m = (a0 + b0) >> 1; if (batch[m] < g) a0 = m + 1; else b0 = m; }
        int a1 = a0, b1 = N_NODES;
        while (a1 < b1) { int m = (a1 + b1) >> 1; if (batch[m] < g + 1) a1 = m + 1; else b1 = m; }
        inv_cnt[g] = 1.0f / (float)max(a1 - a0, 1);
    }
}

// scan1 (fused scanA): deg inline from deg2, dinv written here, block-local prefix.
__global__ __launch_bounds__(256) void k_scan1(const int* __restrict__ deg2,
                                               float* __restrict__ dinv,
                                               int* __restrict__ offs,
                                               int* __restrict__ bsum)
{
    __shared__ int sd[256];
    int t = threadIdx.x;
    int idx = blockIdx.x * 256 + t;
    int v = 0;
    if (idx < N_NODES) {
        for (int s = 0; s < NSLICE; s++) v += deg2[(size_t)s * N_NODES + idx];
        dinv[idx] = rsqrtf((float)v + 1.0f);   // +1 self loop
    }
    sd[t] = v; __syncthreads();
    for (int o = 1; o < 256; o <<= 1) {
        int add = (t >= o) ? sd[t - o] : 0;
        __syncthreads();
        sd[t] += add;
        __syncthreads();
    }
    if (idx < N_NODES) offs[idx] = sd[t] - v;
    if (t == 255) bsum[blockIdx.x] = sd[255];
}

__global__ __launch_bounds__(256) void k_scan2(const int* __restrict__ bsum,
                                               int* __restrict__ boff, int nb)
{
    __shared__ int sd[256];
    int t = threadIdx.x;
    int v = (t < nb) ? bsum[t] : 0;
    sd[t] = v; __syncthreads();
    for (int o = 1; o < 256; o <<= 1) {
        int add = (t >= o) ? sd[t - o] : 0;
        __syncthreads();
        sd[t] += add;
        __syncthreads();
    }
    boff[t] = sd[t] - v;
}

// scan3 + scanC fused: finalize offs, then turn deg2 into per-(node,slice) segment starts.
__global__ __launch_bounds__(256) void k_scan3C(int* __restrict__ offs,
                                                const int* __restrict__ boff,
                                                int* __restrict__ deg2)
{
    int idx = blockIdx.x * 256 + threadIdx.x;
    if (idx < N_NODES) {
        int off = offs[idx] + boff[blockIdx.x];
        offs[idx] = off;
        int run = off;
        for (int s = 0; s < NSLICE; s++) {
            int d = deg2[(size_t)s * N_NODES + idx];
            deg2[(size_t)s * N_NODES + idx] = run;
            run += d;
        }
    } else if (idx == N_NODES) {
        offs[N_NODES] = N_EDGES;
    }
}

// Fill with LDS cursors into pre-reserved disjoint segments (no global atomics).
__global__ __launch_bounds__(256) void k_fill2(const int* __restrict__ row,
                                               const int* __restrict__ col,
                                               const int* __restrict__ offs2,
                                               unsigned short* __restrict__ csr_src)
{
    __shared__ int cur[RSPAN];
    int r = blockIdx.x & (NRANGE - 1);
    int s = blockIdx.x >> 4;
    int lo = r * RSPAN;
    for (int i = threadIdx.x; i < RSPAN; i += 256)
        cur[i] = offs2[(size_t)s * N_NODES + lo + i];
    __syncthreads();
    int e0 = s * ESLICE;
    for (int e = e0 + threadIdx.x; e < e0 + ESLICE; e += 256) {
        int c = col[e] - lo;
        if ((unsigned)c < RSPAN) {
            int p = atomicAdd(&cur[c], 1);
            csr_src[p] = (unsigned short)row[e];
        }
    }
}

// ---- convert x fp32 [N][133] -> bf16 [N][160] with zero K-padding ----
__global__ __launch_bounds__(256) void k_x2bf(const float* __restrict__ x,
                                              unsigned* __restrict__ Abf) // uint = 2 bf16
{
    int idx = blockIdx.x * 256 + threadIdx.x;          // N_NODES * 80
    if (idx >= N_NODES * 80) return;
    int r  = idx / 80;
    int c2 = (idx - r * 80) * 2;
    float a = (c2     < DIM) ? x[(size_t)r * DIM + c2]     : 0.f;
    float b = (c2 + 1 < DIM) ? x[(size_t)r * DIM + c2 + 1] : 0.f;
    Abf[idx] = packbf(a, b);
}

// ---------------- MFMA GEMM: H[M][HSTR](bf16) = A[.][YSTR](bf16) @ W ----------------
__global__ __launch_bounds__(256) void k_gemm_mfma(const unsigned short* __restrict__ A,
                                                   const unsigned short* __restrict__ Wbf,
                                                   unsigned short* __restrict__ H, int M)
{
    int wave = threadIdx.x >> 6, lane = threadIdx.x & 63;
    int quad = lane >> 4, l16 = lane & 15;
    int m = blockIdx.x * 64 + wave * 16 + l16;

    const bf16x8* Arow = (const bf16x8*)(A + (size_t)m * YSTR);
    const bf16x8* Bq   = (const bf16x8*)Wbf;

    f32x4 acc[9] = {};
#pragma unroll
    for (int kc = 0; kc < 5; kc++) {
        bf16x8 af = Arow[kc * 4 + quad];
#pragma unroll
        for (int t = 0; t < 9; t++) {
            bf16x8 bfr = Bq[(t * 5 + kc) * 64 + lane];
            acc[t] = __builtin_amdgcn_mfma_f32_16x16x32_bf16(af, bfr, acc[t], 0, 0, 0);
        }
    }

    int gr0 = blockIdx.x * 64 + wave * 16 + quad * 4;
#pragma unroll
    for (int t = 0; t < 9; t++) {
        int c = t * 16 + l16;
#pragma unroll
        for (int reg = 0; reg < 4; reg++) {
            int gr = gr0 + reg;
            if (gr < M && c < HSTR) {
                float v = (c < DIM) ? acc[t][reg] : 0.f;
                H[(size_t)gr * HSTR + c] = f2bf(v);
            }
        }
    }
}

// ---------------- fused aggregate + bias + ReLU + BN (+ optional mean-pool) ----------------
// 8x-unrolled gather loop (R7 post-mortem: x16/uint2 variant regressed via VGPR/occupancy).

template <bool FINAL>
__global__ __launch_bounds__(256) void k_agg(const unsigned short* __restrict__ h,
                                             const int* __restrict__ offs,
                                             const unsigned short* __restrict__ csr_src,
                                             const float* __restrict__ dinv,
                                             const float* __restrict__ bias,
                                             const float* __restrict__ gam,
                                             const float* __restrict__ bet,
                                             const float* __restrict__ rmean,
                                             const float* __restrict__ rvar,
                                             unsigned short* __restrict__ y,
                                             const int* __restrict__ batch,
                                             const float* __restrict__ inv_cnt,
                                             float* __restrict__ outp)
{
    int node = blockIdx.x * 4 + (threadIdx.x >> 6);
    if (node >= N_NODES) return;
    int lane = threadIdx.x & 63;
    int l2 = lane & 3;

    float di = dinv[node];
    const unsigned* hrow = (const unsigned*)(h + (size_t)node * HSTR);
    unsigned p0 = hrow[lane];        // cols 2*lane, 2*lane+1
    unsigned p1 = hrow[64 + l2];     // cols 128+2*l2 (dup for lanes>=4, discarded)
    float2 a0; a0.x = di * blo(p0); a0.y = di * bhi(p0);   // self-loop term
    float2 a1; a1.x = di * blo(p1); a1.y = di * bhi(p1);

    int s0 = offs[node], s1 = offs[node + 1];
    for (int k0 = s0; k0 < s1; k0 += 64) {
        int nk = min(64, s1 - k0);
        int src = 0; float w = 0.f;
        if (lane < nk) {
            src = csr_src[k0 + lane];
            w   = dinv[src];          // L2-resident 200 KB table
        }
        int j = 0;
        for (; j + 8 <= nk; j += 8) {
            int   ss[8];
            float wv[8];
#pragma unroll
            for (int u = 0; u < 8; u++) {
                ss[u] = __builtin_amdgcn_readfirstlane(__shfl(src, j + u));
                wv[u] = __shfl(w, j + u);
            }
            unsigned q0[8], q1[8];
#pragma unroll
            for (int u = 0; u < 8; u++) {
                const unsigned* r = (const unsigned*)(h + (size_t)ss[u] * HSTR);
                q0[u] = r[lane];
                q1[u] = r[64 + l2];
            }
#pragma unroll
            for (int u = 0; u < 8; u++) {
                a0.x += wv[u] * blo(q0[u]); a0.y += wv[u] * bhi(q0[u]);
                a1.x += wv[u] * blo(q1[u]); a1.y += wv[u] * bhi(q1[u]);
            }
        }
        for (; j < nk; j++) {
            int   s  = __builtin_amdgcn_readfirstlane(__shfl(src, j));
            float ww = __shfl(w, j);
            const unsigned* hr = (const unsigned*)(h + (size_t)s * HSTR);
            unsigned q0 = hr[lane];
            unsigned q1 = hr[64 + l2];
            a0.x += ww * blo(q0); a0.y += ww * bhi(q0);
            a1.x += ww * blo(q1); a1.y += ww * bhi(q1);
        }
    }

    float ic = 0.f; int bg = 0;
    if (FINAL) { bg = batch[node]; ic = inv_cnt[bg]; }

    // main pair: cols 2*lane, 2*lane+1 (both < 128 < DIM)
    {
        int c = 2 * lane;
        float va = di * a0.x + bias[c];
        va = fmaxf(va, 0.f);
        va = (va - rmean[c]) * (gam[c] * rsqrtf(rvar[c] + EPSV)) + bet[c];
        int c1 = c + 1;
        float vb = di * a0.y + bias[c1];
        vb = fmaxf(vb, 0.f);
        vb = (vb - rmean[c1]) * (gam[c1] * rsqrtf(rvar[c1] + EPSV)) + bet[c1];
        if (FINAL) {
            atomicAdd(&outp[(size_t)bg * DIM + c],  va * ic);
            atomicAdd(&outp[(size_t)bg * DIM + c1], vb * ic);
        } else {
            ((unsigned*)(y + (size_t)node * YSTR))[lane] = packbf(va, vb);
        }
    }
    // tail: cols 128..159. lanes 0-3 compute cols 128+2*l2 (masked >=133); lanes 4-15 pad zeros.
    if (lane < 16) {
        float va = 0.f, vb = 0.f;
        if (lane < 4) {
            int c = 128 + 2 * l2;
            if (c < DIM) {
                va = di * a1.x + bias[c];
                va = fmaxf(va, 0.f);
                va = (va - rmean[c]) * (gam[c] * rsqrtf(rvar[c] + EPSV)) + bet[c];
            }
            int c1 = c + 1;
            if (c1 < DIM) {
                vb = di * a1.y + bias[c1];
                vb = fmaxf(vb, 0.f);
                vb = (vb - rmean[c1]) * (gam[c1] * rsqrtf(rvar[c1] + EPSV)) + bet[c1];
            }
            if (FINAL) {
                if (c  < DIM) atomicAdd(&outp[(size_t)bg * DIM + c],  va * ic);
                if (c1 < DIM) atomicAdd(&outp[(size_t)bg * DIM + c1], vb * ic);
            }
        }
        if (!FINAL)
            ((unsigned*)(y + (size_t)node * YSTR))[64 + lane] = packbf(va, vb);
    }
}

// ---------------- launch ----------------

extern "C" void kernel_launch(void* const* d_in, const int* in_sizes, int n_in,
                              void* d_out, int out_size, void* d_ws, size_t ws_size,
                              hipStream_t stream)
{
    const float* x   = (const float*)d_in[0];
    const int*   ei  = (const int*)d_in[1];
    const int*   bat = (const int*)d_in[2];
    const float* W1  = (const float*)d_in[3];
    const float* b1  = (const float*)d_in[4];
    const float* W2  = (const float*)d_in[5];
    const float* b2  = (const float*)d_in[6];
    const float* g1  = (const float*)d_in[7];
    const float* be1 = (const float*)d_in[8];
    const float* rm1 = (const float*)d_in[9];
    const float* rv1 = (const float*)d_in[10];
    const float* g2  = (const float*)d_in[11];
    const float* be2 = (const float*)d_in[12];
    const float* rm2 = (const float*)d_in[13];
    const float* rv2 = (const float*)d_in[14];
    float* outp = (float*)d_out;
    char* ws = (char*)d_ws;

    int*   offs    = (int*)  (ws + 200000);    // 200016 B (N+1 ints)
    float* dinv    = (float*)(ws + 400016);    // 200000 B
    float* inv_cnt = (float*)(ws + 600016);    //   8192 B
    int*   bsum    = (int*)  (ws + 608208);    //   1024 B
    int*   boff    = (int*)  (ws + 609232);    //   1024 B
    unsigned short* csr_src = (unsigned short*)(ws + 610256);   // 3.2 MB
    unsigned short* Wbf1 = (unsigned short*)(ws + 3810256);     // 46080 B
    unsigned short* Wbf2 = (unsigned short*)(ws + 3856336);     // 46080 B
    unsigned short* Abf  = (unsigned short*)(ws + 3902416);     // 16015360 B (50048 x 160)
    unsigned short* Hb   = (unsigned short*)(ws + 19917776);    // 13613056 B (50048 x 136)
    unsigned short* Y1   = (unsigned short*)(ws + 33530832);    // 16015360 B (50048 x 160)
    // deg2/offs2 (128 x 50000 ints = 25.6 MB) aliases Hb+Y1: lifetime ends
    // (k_fill2) before Hb is first written (k_gemm_mfma #1).
    int* deg2 = (int*)(ws + 19917776);

    hipMemsetAsync(d_out, 0, (size_t)out_size * 4, stream);

    const int* row = ei;
    const int* col = ei + N_EDGES;

    int nbl = (N_NODES + 255) / 256;

    k_count2<<<dim3(NSLICE * NRANGE), dim3(256), 0, stream>>>(col, deg2);
    k_setup <<<dim3(189), dim3(256), 0, stream>>>(W1, W2, Wbf1, Wbf2, bat, inv_cnt);
    k_scan1 <<<dim3(nbl), dim3(256), 0, stream>>>(deg2, dinv, offs, bsum);
    k_scan2 <<<dim3(1),   dim3(256), 0, stream>>>(bsum, boff, nbl);
    k_scan3C<<<dim3(nbl), dim3(256), 0, stream>>>(offs, boff, deg2);
    k_fill2 <<<dim3(NSLICE * NRANGE), dim3(256), 0, stream>>>(row, col, deg2, csr_src);

    k_x2bf<<<dim3((N_NODES * 80 + 255) / 256), dim3(256), 0, stream>>>(x, (unsigned*)Abf);

    int gbl = N_ROWS / 64;   // 782
    k_gemm_mfma<<<dim3(gbl), dim3(256), 0, stream>>>(Abf, Wbf1, Hb, N_NODES);
    k_agg<false><<<dim3(N_NODES / 4), dim3(256), 0, stream>>>(Hb, offs, csr_src, dinv,
                                                              b1, g1, be1, rm1, rv1,
                                                              Y1, nullptr, nullptr, nullptr);
    k_gemm_mfma<<<dim3(gbl), dim3(256), 0, stream>>>(Y1, Wbf2, Hb, N_NODES);
    k_agg<true><<<dim3(N_NODES / 4), dim3(256), 0, stream>>>(Hb, offs, csr_src, dinv,
                                                             b2, g2, be2, rm2, rv2,
                                                             nullptr, bat, inv_cnt, outp);
}

// Round 12
// 357.162 us; speedup vs baseline: 1.3707x; 1.0669x over previous
//
#include <hip/hip_runtime.h>

#define N_NODES  50000
#define N_ROWS   50048        // padded row count (multiple of 64)
#define N_EDGES  1600000
#define N_GRAPHS 2048
#define DIM      133
#define HSTR     136          // bf16 row stride for gemm-output / agg-input buffers
#define YSTR     160          // bf16 row stride for gemm-input buffers (K padded to 160)
#define EPSV     1e-5f
#define NRANGE   16
#define RSPAN    3125         // N_NODES / NRANGE
#define NSLICE   64
#define BUCKCAP  110000       // per-bucket capacity (mean 100K, 30+ sigma slack)
#define EPB      1563         // edges per partition block (1024 * 1563 >= N_EDGES)

typedef __attribute__((ext_vector_type(8))) short bf16x8;
typedef __attribute__((ext_vector_type(4))) float f32x4;

// ---- bf16 helpers (raw ushort; bf16 = top 16 bits of fp32) ----
__device__ __forceinline__ float blo(unsigned u) { return __uint_as_float(u << 16); }
__device__ __forceinline__ float bhi(unsigned u) { return __uint_as_float(u & 0xFFFF0000u); }
__device__ __forceinline__ unsigned short f2bf(float x) {
    unsigned v = __float_as_uint(x);
    return (unsigned short)((v + 0x7FFFu + ((v >> 16) & 1u)) >> 16);  // RNE
}
__device__ __forceinline__ unsigned packbf(float a, float b) {
    return (unsigned)f2bf(a) | ((unsigned)f2bf(b) << 16);
}

// ---------------- CSR build: radix partition + per-range hist/fill ----------------

// One pass: partition edges into 16 dest-range buckets, packed 4B records
// (row<<12)|(col-lo). 16 global atomics per block for reservation only.
__global__ __launch_bounds__(256) void k_part(const int* __restrict__ row,
                                              const int* __restrict__ col,
                                              int* __restrict__ bcnt,
                                              unsigned* __restrict__ buckets)
{
    __shared__ int cnt[NRANGE];
    __shared__ int cur[NRANGE];
    int e0 = blockIdx.x * EPB;
    if (threadIdx.x < NRANGE) cnt[threadIdx.x] = 0;
    __syncthreads();
    int e1 = min(e0 + EPB, N_EDGES);
    for (int e = e0 + threadIdx.x; e < e1; e += 256)
        atomicAdd(&cnt[col[e] / RSPAN], 1);
    __syncthreads();
    if (threadIdx.x < NRANGE)
        cur[threadIdx.x] = atomicAdd(&bcnt[threadIdx.x], cnt[threadIdx.x]);
    __syncthreads();
    for (int e = e0 + threadIdx.x; e < e1; e += 256) {
        int c = col[e];
        int r = c / RSPAN;
        int p = atomicAdd(&cur[r], 1);
        buckets[(size_t)r * BUCKCAP + p] =
            ((unsigned)row[e] << 12) | (unsigned)(c - r * RSPAN);
    }
}

// Block (r,s): LDS histogram over its slice of bucket r -> deg2[s][r-range].
__global__ __launch_bounds__(256) void k_count2(const unsigned* __restrict__ buckets,
                                                const int* __restrict__ bcnt,
                                                int* __restrict__ deg2)
{
    __shared__ int hist[RSPAN];
    int r = blockIdx.x & (NRANGE - 1);
    int s = blockIdx.x >> 4;
    int lo = r * RSPAN;
    for (int i = threadIdx.x; i < RSPAN; i += 256) hist[i] = 0;
    __syncthreads();
    int n = bcnt[r];
    int chunk = (n + NSLICE - 1) / NSLICE;
    int e0 = s * chunk, e1 = min(e0 + chunk, n);
    const unsigned* b = buckets + (size_t)r * BUCKCAP;
    for (int e = e0 + threadIdx.x; e < e1; e += 256)
        atomicAdd(&hist[b[e] & 0xFFFu], 1);
    __syncthreads();
    for (int i = threadIdx.x; i < RSPAN; i += 256)
        deg2[(size_t)s * N_NODES + lo + i] = hist[i];
}

// Combined small setup: pack W1,W2 into MFMA B-layout + per-graph inv counts.
__device__ __forceinline__ void w2bf_one(const float* __restrict__ W,
                                         unsigned short* __restrict__ Wbf, int idx)
{
    int j    = idx & 7;
    int lane = (idx >> 3) & 63;
    int kc   = (idx >> 9) % 5;
    int t    = idx / (8 * 64 * 5);
    int k = kc * 32 + (lane >> 4) * 8 + j;
    int n = t * 16 + (lane & 15);
    float v = (k < DIM && n < DIM) ? W[k * DIM + n] : 0.f;
    Wbf[idx] = f2bf(v);
}

__global__ __launch_bounds__(256) void k_setup(const float* __restrict__ W1,
                                               const float* __restrict__ W2,
                                               unsigned short* __restrict__ Wbf1,
                                               unsigned short* __restrict__ Wbf2,
                                               const int* __restrict__ batch,
                                               float* __restrict__ inv_cnt)
{
    int tid = blockIdx.x * 256 + threadIdx.x;
    if (tid < 23040) {
        w2bf_one(W1, Wbf1, tid);
    } else if (tid < 46080) {
        w2bf_one(W2, Wbf2, tid - 23040);
    } else if (tid < 46080 + N_GRAPHS) {
        int g = tid - 46080;                    // batch SORTED: binary search
        int a0 = 0, b0 = N_NODES;
        while (a0 < b0) { int m = (a0 + b0) >> 1; if (batch[m] < g) a0 = m + 1; else b0 = m; }
        int a1 = a0, b1 = N_NODES;
        while (a1 < b1) { int m = (a1 + b1) >> 1; if (batch[m] < g + 1) a1 = m + 1; else b1 = m; }
        inv_cnt[g] = 1.0f / (float)max(a1 - a0, 1);
    }
}

// scan1: deg inline from deg2 (sum over slices), dinv fused, block-local prefix.
__global__ __launch_bounds__(256) void k_scan1(const int* __restrict__ deg2,
                                               float* __restrict__ dinv,
                                               int* __restrict__ offs,
                                               int* __restrict__ bsum)
{
    __shared__ int sd[256];
    int t = threadIdx.x;
    int idx = blockIdx.x * 256 + t;
    int v = 0;
    if (idx < N_NODES) {
        for (int s = 0; s < NSLICE; s++) v += deg2[(size_t)s * N_NODES + idx];
        dinv[idx] = rsqrtf((float)v + 1.0f);   // +1 self loop
    }
    sd[t] = v; __syncthreads();
    for (int o = 1; o < 256; o <<= 1) {
        int add = (t >= o) ? sd[t - o] : 0;
        __syncthreads();
        sd[t] += add;
        __syncthreads();
    }
    if (idx < N_NODES) offs[idx] = sd[t] - v;
    if (t == 255) bsum[blockIdx.x] = sd[255];
}

__global__ __launch_bounds__(256) void k_scan2(const int* __restrict__ bsum,
                                               int* __restrict__ boff, int nb)
{
    __shared__ int sd[256];
    int t = threadIdx.x;
    int v = (t < nb) ? bsum[t] : 0;
    sd[t] = v; __syncthreads();
    for (int o = 1; o < 256; o <<= 1) {
        int add = (t >= o) ? sd[t - o] : 0;
        __syncthreads();
        sd[t] += add;
        __syncthreads();
    }
    boff[t] = sd[t] - v;
}

// scan3 + scanC fused: finalize offs, then turn deg2 into per-(node,slice) segment starts.
__global__ __launch_bounds__(256) void k_scan3C(int* __restrict__ offs,
                                                const int* __restrict__ boff,
                                                int* __restrict__ deg2)
{
    int idx = blockIdx.x * 256 + threadIdx.x;
    if (idx < N_NODES) {
        int off = offs[idx] + boff[blockIdx.x];
        offs[idx] = off;
        int run = off;
        for (int s = 0; s < NSLICE; s++) {
            int d = deg2[(size_t)s * N_NODES + idx];
            deg2[(size_t)s * N_NODES + idx] = run;
            run += d;
        }
    } else if (idx == N_NODES) {
        offs[N_NODES] = N_EDGES;
    }
}

// Block (r,s): fill from packed bucket slice via LDS cursors (no global atomics).
__global__ __launch_bounds__(256) void k_fill2(const unsigned* __restrict__ buckets,
                                               const int* __restrict__ bcnt,
                                               const int* __restrict__ offs2,
                                               unsigned short* __restrict__ csr_src)
{
    __shared__ int cur[RSPAN];
    int r = blockIdx.x & (NRANGE - 1);
    int s = blockIdx.x >> 4;
    int lo = r * RSPAN;
    for (int i = threadIdx.x; i < RSPAN; i += 256)
        cur[i] = offs2[(size_t)s * N_NODES + lo + i];
    __syncthreads();
    int n = bcnt[r];
    int chunk = (n + NSLICE - 1) / NSLICE;
    int e0 = s * chunk, e1 = min(e0 + chunk, n);
    const unsigned* b = buckets + (size_t)r * BUCKCAP;
    for (int e = e0 + threadIdx.x; e < e1; e += 256) {
        unsigned v = b[e];
        int p = atomicAdd(&cur[v & 0xFFFu], 1);
        csr_src[p] = (unsigned short)(v >> 12);
    }
}

// ---- convert x fp32 [N][133] -> bf16 [N][160] with zero K-padding ----
__global__ __launch_bounds__(256) void k_x2bf(const float* __restrict__ x,
                                              unsigned* __restrict__ Abf) // uint = 2 bf16
{
    int idx = blockIdx.x * 256 + threadIdx.x;          // N_NODES * 80
    if (idx >= N_NODES * 80) return;
    int r  = idx / 80;
    int c2 = (idx - r * 80) * 2;
    float a = (c2     < DIM) ? x[(size_t)r * DIM + c2]     : 0.f;
    float b = (c2 + 1 < DIM) ? x[(size_t)r * DIM + c2 + 1] : 0.f;
    Abf[idx] = packbf(a, b);
}

// ---------------- MFMA GEMM: H[M][HSTR](bf16) = A[.][YSTR](bf16) @ W ----------------
__global__ __launch_bounds__(256) void k_gemm_mfma(const unsigned short* __restrict__ A,
                                                   const unsigned short* __restrict__ Wbf,
                                                   unsigned short* __restrict__ H, int M)
{
    int wave = threadIdx.x >> 6, lane = threadIdx.x & 63;
    int quad = lane >> 4, l16 = lane & 15;
    int m = blockIdx.x * 64 + wave * 16 + l16;

    const bf16x8* Arow = (const bf16x8*)(A + (size_t)m * YSTR);
    const bf16x8* Bq   = (const bf16x8*)Wbf;

    f32x4 acc[9] = {};
#pragma unroll
    for (int kc = 0; kc < 5; kc++) {
        bf16x8 af = Arow[kc * 4 + quad];
#pragma unroll
        for (int t = 0; t < 9; t++) {
            bf16x8 bfr = Bq[(t * 5 + kc) * 64 + lane];
            acc[t] = __builtin_amdgcn_mfma_f32_16x16x32_bf16(af, bfr, acc[t], 0, 0, 0);
        }
    }

    int gr0 = blockIdx.x * 64 + wave * 16 + quad * 4;
#pragma unroll
    for (int t = 0; t < 9; t++) {
        int c = t * 16 + l16;
#pragma unroll
        for (int reg = 0; reg < 4; reg++) {
            int gr = gr0 + reg;
            if (gr < M && c < HSTR) {
                float v = (c < DIM) ? acc[t][reg] : 0.f;
                H[(size_t)gr * HSTR + c] = f2bf(v);
            }
        }
    }
}

// ---------------- fused aggregate + bias + ReLU + BN (+ optional mean-pool) ----------------
// 8x-unrolled gather loop (R7 post-mortem: x16/uint2 variant regressed via VGPR/occupancy).

template <bool FINAL>
__global__ __launch_bounds__(256) void k_agg(const unsigned short* __restrict__ h,
                                             const int* __restrict__ offs,
                                             const unsigned short* __restrict__ csr_src,
                                             const float* __restrict__ dinv,
                                             const float* __restrict__ bias,
                                             const float* __restrict__ gam,
                                             const float* __restrict__ bet,
                                             const float* __restrict__ rmean,
                                             const float* __restrict__ rvar,
                                             unsigned short* __restrict__ y,
                                             const int* __restrict__ batch,
                                             const float* __restrict__ inv_cnt,
                                             float* __restrict__ outp)
{
    int node = blockIdx.x * 4 + (threadIdx.x >> 6);
    if (node >= N_NODES) return;
    int lane = threadIdx.x & 63;
    int l2 = lane & 3;

    float di = dinv[node];
    const unsigned* hrow = (const unsigned*)(h + (size_t)node * HSTR);
    unsigned p0 = hrow[lane];        // cols 2*lane, 2*lane+1
    unsigned p1 = hrow[64 + l2];     // cols 128+2*l2 (dup for lanes>=4, discarded)
    float2 a0; a0.x = di * blo(p0); a0.y = di * bhi(p0);   // self-loop term
    float2 a1; a1.x = di * blo(p1); a1.y = di * bhi(p1);

    int s0 = offs[node], s1 = offs[node + 1];
    for (int k0 = s0; k0 < s1; k0 += 64) {
        int nk = min(64, s1 - k0);
        int src = 0; float w = 0.f;
        if (lane < nk) {
            src = csr_src[k0 + lane];
            w   = dinv[src];          // L2-resident 200 KB table
        }
        int j = 0;
        for (; j + 8 <= nk; j += 8) {
            int   ss[8];
            float wv[8];
#pragma unroll
            for (int u = 0; u < 8; u++) {
                ss[u] = __builtin_amdgcn_readfirstlane(__shfl(src, j + u));
                wv[u] = __shfl(w, j + u);
            }
            unsigned q0[8], q1[8];
#pragma unroll
            for (int u = 0; u < 8; u++) {
                const unsigned* r = (const unsigned*)(h + (size_t)ss[u] * HSTR);
                q0[u] = r[lane];
                q1[u] = r[64 + l2];
            }
#pragma unroll
            for (int u = 0; u < 8; u++) {
                a0.x += wv[u] * blo(q0[u]); a0.y += wv[u] * bhi(q0[u]);
                a1.x += wv[u] * blo(q1[u]); a1.y += wv[u] * bhi(q1[u]);
            }
        }
        for (; j < nk; j++) {
            int   s  = __builtin_amdgcn_readfirstlane(__shfl(src, j));
            float ww = __shfl(w, j);
            const unsigned* hr = (const unsigned*)(h + (size_t)s * HSTR);
            unsigned q0 = hr[lane];
            unsigned q1 = hr[64 + l2];
            a0.x += ww * blo(q0); a0.y += ww * bhi(q0);
            a1.x += ww * blo(q1); a1.y += ww * bhi(q1);
        }
    }

    float ic = 0.f; int bg = 0;
    if (FINAL) { bg = batch[node]; ic = inv_cnt[bg]; }

    // main pair: cols 2*lane, 2*lane+1 (both < 128 < DIM)
    {
        int c = 2 * lane;
        float va = di * a0.x + bias[c];
        va = fmaxf(va, 0.f);
        va = (va - rmean[c]) * (gam[c] * rsqrtf(rvar[c] + EPSV)) + bet[c];
        int c1 = c + 1;
        float vb = di * a0.y + bias[c1];
        vb = fmaxf(vb, 0.f);
        vb = (vb - rmean[c1]) * (gam[c1] * rsqrtf(rvar[c1] + EPSV)) + bet[c1];
        if (FINAL) {
            atomicAdd(&outp[(size_t)bg * DIM + c],  va * ic);
            atomicAdd(&outp[(size_t)bg * DIM + c1], vb * ic);
        } else {
            ((unsigned*)(y + (size_t)node * YSTR))[lane] = packbf(va, vb);
        }
    }
    // tail: cols 128..159. lanes 0-3 compute cols 128+2*l2 (masked >=133); lanes 4-15 pad zeros.
    if (lane < 16) {
        float va = 0.f, vb = 0.f;
        if (lane < 4) {
            int c = 128 + 2 * l2;
            if (c < DIM) {
                va = di * a1.x + bias[c];
                va = fmaxf(va, 0.f);
                va = (va - rmean[c]) * (gam[c] * rsqrtf(rvar[c] + EPSV)) + bet[c];
            }
            int c1 = c + 1;
            if (c1 < DIM) {
                vb = di * a1.y + bias[c1];
                vb = fmaxf(vb, 0.f);
                vb = (vb - rmean[c1]) * (gam[c1] * rsqrtf(rvar[c1] + EPSV)) + bet[c1];
            }
            if (FINAL) {
                if (c  < DIM) atomicAdd(&outp[(size_t)bg * DIM + c],  va * ic);
                if (c1 < DIM) atomicAdd(&outp[(size_t)bg * DIM + c1], vb * ic);
            }
        }
        if (!FINAL)
            ((unsigned*)(y + (size_t)node * YSTR))[64 + lane] = packbf(va, vb);
    }
}

// ---------------- launch ----------------

extern "C" void kernel_launch(void* const* d_in, const int* in_sizes, int n_in,
                              void* d_out, int out_size, void* d_ws, size_t ws_size,
                              hipStream_t stream)
{
    const float* x   = (const float*)d_in[0];
    const int*   ei  = (const int*)d_in[1];
    const int*   bat = (const int*)d_in[2];
    const float* W1  = (const float*)d_in[3];
    const float* b1  = (const float*)d_in[4];
    const float* W2  = (const float*)d_in[5];
    const float* b2  = (const float*)d_in[6];
    const float* g1  = (const float*)d_in[7];
    const float* be1 = (const float*)d_in[8];
    const float* rm1 = (const float*)d_in[9];
    const float* rv1 = (const float*)d_in[10];
    const float* g2  = (const float*)d_in[11];
    const float* be2 = (const float*)d_in[12];
    const float* rm2 = (const float*)d_in[13];
    const float* rv2 = (const float*)d_in[14];
    float* outp = (float*)d_out;
    char* ws = (char*)d_ws;

    int*   bcnt    = (int*)  (ws + 0);         //     64 B (16 bucket counters)
    int*   offs    = (int*)  (ws + 200000);    // 200016 B (N+1 ints)
    float* dinv    = (float*)(ws + 400016);    // 200000 B
    float* inv_cnt = (float*)(ws + 600016);    //   8192 B
    int*   bsum    = (int*)  (ws + 608208);    //   1024 B
    int*   boff    = (int*)  (ws + 609232);    //   1024 B
    unsigned short* csr_src = (unsigned short*)(ws + 610256);   // 3.2 MB
    unsigned short* Wbf1 = (unsigned short*)(ws + 3810256);     // 46080 B
    unsigned short* Wbf2 = (unsigned short*)(ws + 3856336);     // 46080 B
    unsigned short* Abf  = (unsigned short*)(ws + 3902416);     // 16015360 B (50048 x 160)
    unsigned short* Hb   = (unsigned short*)(ws + 19917776);    // 13613056 B (50048 x 136)
    unsigned short* Y1   = (unsigned short*)(ws + 33530832);    // 16015360 B (50048 x 160)
    // CSR-build scratch aliases Hb/Y1 (dead before gemm1 writes Hb):
    unsigned* buckets = (unsigned*)(ws + 19917776);             // 16 x 110000 x 4 = 7.04 MB
    int*      deg2    = (int*)    (ws + 26957776);              // 64 x 50000 x 4 = 12.8 MB

    hipMemsetAsync(bcnt, 0, 64, stream);
    hipMemsetAsync(d_out, 0, (size_t)out_size * 4, stream);

    const int* row = ei;
    const int* col = ei + N_EDGES;

    int nbl = (N_NODES + 255) / 256;

    k_part  <<<dim3(1024), dim3(256), 0, stream>>>(row, col, bcnt, buckets);
    k_setup <<<dim3(189), dim3(256), 0, stream>>>(W1, W2, Wbf1, Wbf2, bat, inv_cnt);
    k_count2<<<dim3(NSLICE * NRANGE), dim3(256), 0, stream>>>(buckets, bcnt, deg2);
    k_scan1 <<<dim3(nbl), dim3(256), 0, stream>>>(deg2, dinv, offs, bsum);
    k_scan2 <<<dim3(1),   dim3(256), 0, stream>>>(bsum, boff, nbl);
    k_scan3C<<<dim3(nbl), dim3(256), 0, stream>>>(offs, boff, deg2);
    k_fill2 <<<dim3(NSLICE * NRANGE), dim3(256), 0, stream>>>(buckets, bcnt, deg2, csr_src);

    k_x2bf<<<dim3((N_NODES * 80 + 255) / 256), dim3(256), 0, stream>>>(x, (unsigned*)Abf);

    int gbl = N_ROWS / 64;   // 782
    k_gemm_mfma<<<dim3(gbl), dim3(256), 0, stream>>>(Abf, Wbf1, Hb, N_NODES);
    k_agg<false><<<dim3(N_NODES / 4), dim3(256), 0, stream>>>(Hb, offs, csr_src, dinv,
                                                              b1, g1, be1, rm1, rv1,
                                                              Y1, nullptr, nullptr, nullptr);
    k_gemm_mfma<<<dim3(gbl), dim3(256), 0, stream>>>(Y1, Wbf2, Hb, N_NODES);
    k_agg<true><<<dim3(N_NODES / 4), dim3(256), 0, stream>>>(Hb, offs, csr_src, dinv,
                                                             b2, g2, be2, rm2, rv2,
                                                             nullptr, bat, inv_cnt, outp);
}

// Round 13
// 352.992 us; speedup vs baseline: 1.3869x; 1.0118x over previous
//
#include <hip/hip_runtime.h>

#define N_NODES  50000
#define N_ROWS   50048        // padded row count (multiple of 64)
#define N_EDGES  1600000
#define N_GRAPHS 2048
#define DIM      133
#define HSTR     136          // bf16 row stride for gemm-output / agg-input buffers
#define YSTR     160          // bf16 row stride for gemm-input buffers (K padded to 160)
#define EPSV     1e-5f
#define NRANGE   16
#define RSPAN    3125         // N_NODES / NRANGE
#define NSLICE   64
#define BUCKCAP  110000       // per-bucket capacity (mean 100K, 30+ sigma slack)
#define EPB      1563         // edges per partition block (1024 * 1563 >= N_EDGES)

typedef __attribute__((ext_vector_type(8))) short bf16x8;
typedef __attribute__((ext_vector_type(4))) float f32x4;

// ---- bf16 helpers (raw ushort; bf16 = top 16 bits of fp32) ----
__device__ __forceinline__ float blo(unsigned u) { return __uint_as_float(u << 16); }
__device__ __forceinline__ float bhi(unsigned u) { return __uint_as_float(u & 0xFFFF0000u); }
__device__ __forceinline__ unsigned short f2bf(float x) {
    unsigned v = __float_as_uint(x);
    return (unsigned short)((v + 0x7FFFu + ((v >> 16) & 1u)) >> 16);  // RNE
}
__device__ __forceinline__ unsigned packbf(float a, float b) {
    return (unsigned)f2bf(a) | ((unsigned)f2bf(b) << 16);
}

// ---------------- CSR build: radix partition + per-range hist/fill ----------------

// One pass: partition edges into 16 dest-range buckets, packed 4B records
// (row<<12)|(col-lo). 16 global atomics per block for reservation only.
__global__ __launch_bounds__(256) void k_part(const int* __restrict__ row,
                                              const int* __restrict__ col,
                                              int* __restrict__ bcnt,
                                              unsigned* __restrict__ buckets)
{
    __shared__ int cnt[NRANGE];
    __shared__ int cur[NRANGE];
    int e0 = blockIdx.x * EPB;
    if (threadIdx.x < NRANGE) cnt[threadIdx.x] = 0;
    __syncthreads();
    int e1 = min(e0 + EPB, N_EDGES);
    for (int e = e0 + threadIdx.x; e < e1; e += 256)
        atomicAdd(&cnt[col[e] / RSPAN], 1);
    __syncthreads();
    if (threadIdx.x < NRANGE)
        cur[threadIdx.x] = atomicAdd(&bcnt[threadIdx.x], cnt[threadIdx.x]);
    __syncthreads();
    for (int e = e0 + threadIdx.x; e < e1; e += 256) {
        int c = col[e];
        int r = c / RSPAN;
        int p = atomicAdd(&cur[r], 1);
        buckets[(size_t)r * BUCKCAP + p] =
            ((unsigned)row[e] << 12) | (unsigned)(c - r * RSPAN);
    }
}

// Block (r,s): LDS histogram over its slice of bucket r -> deg2[s][r-range].
__global__ __launch_bounds__(256) void k_count2(const unsigned* __restrict__ buckets,
                                                const int* __restrict__ bcnt,
                                                int* __restrict__ deg2)
{
    __shared__ int hist[RSPAN];
    int r = blockIdx.x & (NRANGE - 1);
    int s = blockIdx.x >> 4;
    int lo = r * RSPAN;
    for (int i = threadIdx.x; i < RSPAN; i += 256) hist[i] = 0;
    __syncthreads();
    int n = bcnt[r];
    int chunk = (n + NSLICE - 1) / NSLICE;
    int e0 = s * chunk, e1 = min(e0 + chunk, n);
    const unsigned* b = buckets + (size_t)r * BUCKCAP;
    for (int e = e0 + threadIdx.x; e < e1; e += 256)
        atomicAdd(&hist[b[e] & 0xFFFu], 1);
    __syncthreads();
    for (int i = threadIdx.x; i < RSPAN; i += 256)
        deg2[(size_t)s * N_NODES + lo + i] = hist[i];
}

// Fused: x->bf16 conversion (blocks 0..15624) + W-pack/inv_cnt setup (rest).
__device__ __forceinline__ void w2bf_one(const float* __restrict__ W,
                                         unsigned short* __restrict__ Wbf, int idx)
{
    int j    = idx & 7;
    int lane = (idx >> 3) & 63;
    int kc   = (idx >> 9) % 5;
    int t    = idx / (8 * 64 * 5);
    int k = kc * 32 + (lane >> 4) * 8 + j;
    int n = t * 16 + (lane & 15);
    float v = (k < DIM && n < DIM) ? W[k * DIM + n] : 0.f;
    Wbf[idx] = f2bf(v);
}

#define X2BF_BLOCKS 15625     // N_NODES*80 / 256

__global__ __launch_bounds__(256) void k_prep(const float* __restrict__ x,
                                              unsigned* __restrict__ Abf,
                                              const float* __restrict__ W1,
                                              const float* __restrict__ W2,
                                              unsigned short* __restrict__ Wbf1,
                                              unsigned short* __restrict__ Wbf2,
                                              const int* __restrict__ batch,
                                              float* __restrict__ inv_cnt)
{
    if (blockIdx.x < X2BF_BLOCKS) {
        int idx = blockIdx.x * 256 + threadIdx.x;          // N_NODES * 80
        if (idx >= N_NODES * 80) return;
        int r  = idx / 80;
        int c2 = (idx - r * 80) * 2;
        float a = (c2     < DIM) ? x[(size_t)r * DIM + c2]     : 0.f;
        float b = (c2 + 1 < DIM) ? x[(size_t)r * DIM + c2 + 1] : 0.f;
        Abf[idx] = packbf(a, b);
        return;
    }
    int tid = (blockIdx.x - X2BF_BLOCKS) * 256 + threadIdx.x;
    if (tid < 23040) {
        w2bf_one(W1, Wbf1, tid);
    } else if (tid < 46080) {
        w2bf_one(W2, Wbf2, tid - 23040);
    } else if (tid < 46080 + N_GRAPHS) {
        int g = tid - 46080;                    // batch SORTED: binary search
        int a0 = 0, b0 = N_NODES;
        while (a0 < b0) { int m = (a0 + b0) >> 1; if (batch[m] < g) a0 = m + 1; else b0 = m; }
        int a1 = a0, b1 = N_NODES;
        while (a1 < b1) { int m = (a1 + b1) >> 1; if (batch[m] < g + 1) a1 = m + 1; else b1 = m; }
        inv_cnt[g] = 1.0f / (float)max(a1 - a0, 1);
    }
}

// scan1: deg inline from deg2 (sum over slices), dinv fused, block-local prefix.
__global__ __launch_bounds__(256) void k_scan1(const int* __restrict__ deg2,
                                               float* __restrict__ dinv,
                                               int* __restrict__ offs,
                                               int* __restrict__ bsum)
{
    __shared__ int sd[256];
    int t = threadIdx.x;
    int idx = blockIdx.x * 256 + t;
    int v = 0;
    if (idx < N_NODES) {
        for (int s = 0; s < NSLICE; s++) v += deg2[(size_t)s * N_NODES + idx];
        dinv[idx] = rsqrtf((float)v + 1.0f);   // +1 self loop
    }
    sd[t] = v; __syncthreads();
    for (int o = 1; o < 256; o <<= 1) {
        int add = (t >= o) ? sd[t - o] : 0;
        __syncthreads();
        sd[t] += add;
        __syncthreads();
    }
    if (idx < N_NODES) offs[idx] = sd[t] - v;
    if (t == 255) bsum[blockIdx.x] = sd[255];
}

__global__ __launch_bounds__(256) void k_scan2(const int* __restrict__ bsum,
                                               int* __restrict__ boff, int nb)
{
    __shared__ int sd[256];
    int t = threadIdx.x;
    int v = (t < nb) ? bsum[t] : 0;
    sd[t] = v; __syncthreads();
    for (int o = 1; o < 256; o <<= 1) {
        int add = (t >= o) ? sd[t - o] : 0;
        __syncthreads();
        sd[t] += add;
        __syncthreads();
    }
    boff[t] = sd[t] - v;
}

// scan3 + scanC fused: finalize offs, then turn deg2 into per-(node,slice) segment starts.
__global__ __launch_bounds__(256) void k_scan3C(int* __restrict__ offs,
                                                const int* __restrict__ boff,
                                                int* __restrict__ deg2)
{
    int idx = blockIdx.x * 256 + threadIdx.x;
    if (idx < N_NODES) {
        int off = offs[idx] + boff[blockIdx.x];
        offs[idx] = off;
        int run = off;
        for (int s = 0; s < NSLICE; s++) {
            int d = deg2[(size_t)s * N_NODES + idx];
            deg2[(size_t)s * N_NODES + idx] = run;
            run += d;
        }
    } else if (idx == N_NODES) {
        offs[N_NODES] = N_EDGES;
    }
}

// Block (r,s): fill from packed bucket slice via LDS cursors.
// CSR record: (src<<16) | bf16(dinv[src]) -- self-contained 4B for scalar-pipe agg.
__global__ __launch_bounds__(256) void k_fill2(const unsigned* __restrict__ buckets,
                                               const int* __restrict__ bcnt,
                                               const int* __restrict__ offs2,
                                               const float* __restrict__ dinv,
                                               unsigned* __restrict__ csr)
{
    __shared__ int cur[RSPAN];
    int r = blockIdx.x & (NRANGE - 1);
    int s = blockIdx.x >> 4;
    int lo = r * RSPAN;
    for (int i = threadIdx.x; i < RSPAN; i += 256)
        cur[i] = offs2[(size_t)s * N_NODES + lo + i];
    __syncthreads();
    int n = bcnt[r];
    int chunk = (n + NSLICE - 1) / NSLICE;
    int e0 = s * chunk, e1 = min(e0 + chunk, n);
    const unsigned* b = buckets + (size_t)r * BUCKCAP;
    for (int e = e0 + threadIdx.x; e < e1; e += 256) {
        unsigned v = b[e];
        int src = (int)(v >> 12);
        int p = atomicAdd(&cur[v & 0xFFFu], 1);
        csr[p] = ((unsigned)src << 16) | (unsigned)f2bf(dinv[src]);
    }
}

// ---------------- MFMA GEMM: H[M][HSTR](bf16) = A[.][YSTR](bf16) @ W ----------------
__global__ __launch_bounds__(256) void k_gemm_mfma(const unsigned short* __restrict__ A,
                                                   const unsigned short* __restrict__ Wbf,
                                                   unsigned short* __restrict__ H, int M)
{
    int wave = threadIdx.x >> 6, lane = threadIdx.x & 63;
    int quad = lane >> 4, l16 = lane & 15;
    int m = blockIdx.x * 64 + wave * 16 + l16;

    const bf16x8* Arow = (const bf16x8*)(A + (size_t)m * YSTR);
    const bf16x8* Bq   = (const bf16x8*)Wbf;

    f32x4 acc[9] = {};
#pragma unroll
    for (int kc = 0; kc < 5; kc++) {
        bf16x8 af = Arow[kc * 4 + quad];
#pragma unroll
        for (int t = 0; t < 9; t++) {
            bf16x8 bfr = Bq[(t * 5 + kc) * 64 + lane];
            acc[t] = __builtin_amdgcn_mfma_f32_16x16x32_bf16(af, bfr, acc[t], 0, 0, 0);
        }
    }

    int gr0 = blockIdx.x * 64 + wave * 16 + quad * 4;
#pragma unroll
    for (int t = 0; t < 9; t++) {
        int c = t * 16 + l16;
#pragma unroll
        for (int reg = 0; reg < 4; reg++) {
            int gr = gr0 + reg;
            if (gr < M && c < HSTR) {
                float v = (c < DIM) ? acc[t][reg] : 0.f;
                H[(size_t)gr * HSTR + c] = f2bf(v);
            }
        }
    }
}

// ---------------- fused aggregate + bias + ReLU + BN (+ optional mean-pool) ----------------
// Scalar-pipe edge stream: node forced wave-uniform via readfirstlane -> csr[e]
// is a uniform address (s_load, K$-cached, 16 recs/line); w = bf16 weight via
// scalar shift (SGPR operand to v_fmac); h-row base in SGPR -> zero per-edge
// vector address math. 8x unroll = 16 gathers in flight.

template <bool FINAL>
__global__ __launch_bounds__(256) void k_agg(const unsigned short* __restrict__ h,
                                             const int* __restrict__ offs,
                                             const unsigned* __restrict__ csr,
                                             const float* __restrict__ dinv,
                                             const float* __restrict__ bias,
                                             const float* __restrict__ gam,
                                             const float* __restrict__ bet,
                                             const float* __restrict__ rmean,
                                             const float* __restrict__ rvar,
                                             unsigned short* __restrict__ y,
                                             const int* __restrict__ batch,
                                             const float* __restrict__ inv_cnt,
                                             float* __restrict__ outp)
{
    int node = __builtin_amdgcn_readfirstlane(blockIdx.x * 4 + (threadIdx.x >> 6));
    if (node >= N_NODES) return;
    int lane = threadIdx.x & 63;
    int l2 = lane & 3;

    float di = dinv[node];
    const unsigned* hrow = (const unsigned*)(h + (size_t)node * HSTR);
    unsigned p0 = hrow[lane];        // cols 2*lane, 2*lane+1
    unsigned p1 = hrow[64 + l2];     // cols 128+2*l2 (dup for lanes>=4, discarded)
    float2 a0; a0.x = di * blo(p0); a0.y = di * bhi(p0);   // self-loop term
    float2 a1; a1.x = di * blo(p1); a1.y = di * bhi(p1);

    int s0 = offs[node], s1 = offs[node + 1];
    int e = s0;
    for (; e + 8 <= s1; e += 8) {
        unsigned rec[8];
#pragma unroll
        for (int u = 0; u < 8; u++) rec[u] = csr[e + u];       // uniform -> s_load
        unsigned q0[8], q1[8];
#pragma unroll
        for (int u = 0; u < 8; u++) {
            const unsigned* hr = (const unsigned*)(h + (size_t)(rec[u] >> 16) * HSTR);
            q0[u] = hr[lane];
            q1[u] = hr[64 + l2];
        }
#pragma unroll
        for (int u = 0; u < 8; u++) {
            float w = __uint_as_float(rec[u] << 16);           // bf16 -> f32, scalar shift
            a0.x += w * blo(q0[u]); a0.y += w * bhi(q0[u]);
            a1.x += w * blo(q1[u]); a1.y += w * bhi(q1[u]);
        }
    }
    for (; e < s1; e++) {
        unsigned rec = csr[e];
        float w = __uint_as_float(rec << 16);
        const unsigned* hr = (const unsigned*)(h + (size_t)(rec >> 16) * HSTR);
        unsigned q0 = hr[lane];
        unsigned q1 = hr[64 + l2];
        a0.x += w * blo(q0); a0.y += w * bhi(q0);
        a1.x += w * blo(q1); a1.y += w * bhi(q1);
    }

    float ic = 0.f; int bg = 0;
    if (FINAL) { bg = batch[node]; ic = inv_cnt[bg]; }

    // main pair: cols 2*lane, 2*lane+1 (both < 128 < DIM)
    {
        int c = 2 * lane;
        float va = di * a0.x + bias[c];
        va = fmaxf(va, 0.f);
        va = (va - rmean[c]) * (gam[c] * rsqrtf(rvar[c] + EPSV)) + bet[c];
        int c1 = c + 1;
        float vb = di * a0.y + bias[c1];
        vb = fmaxf(vb, 0.f);
        vb = (vb - rmean[c1]) * (gam[c1] * rsqrtf(rvar[c1] + EPSV)) + bet[c1];
        if (FINAL) {
            atomicAdd(&outp[(size_t)bg * DIM + c],  va * ic);
            atomicAdd(&outp[(size_t)bg * DIM + c1], vb * ic);
        } else {
            ((unsigned*)(y + (size_t)node * YSTR))[lane] = packbf(va, vb);
        }
    }
    // tail: cols 128..159. lanes 0-3 compute cols 128+2*l2 (masked >=133); lanes 4-15 pad zeros.
    if (lane < 16) {
        float va = 0.f, vb = 0.f;
        if (lane < 4) {
            int c = 128 + 2 * l2;
            if (c < DIM) {
                va = di * a1.x + bias[c];
                va = fmaxf(va, 0.f);
                va = (va - rmean[c]) * (gam[c] * rsqrtf(rvar[c] + EPSV)) + bet[c];
            }
            int c1 = c + 1;
            if (c1 < DIM) {
                vb = di * a1.y + bias[c1];
                vb = fmaxf(vb, 0.f);
                vb = (vb - rmean[c1]) * (gam[c1] * rsqrtf(rvar[c1] + EPSV)) + bet[c1];
            }
            if (FINAL) {
                if (c  < DIM) atomicAdd(&outp[(size_t)bg * DIM + c],  va * ic);
                if (c1 < DIM) atomicAdd(&outp[(size_t)bg * DIM + c1], vb * ic);
            }
        }
        if (!FINAL)
            ((unsigned*)(y + (size_t)node * YSTR))[64 + lane] = packbf(va, vb);
    }
}

// ---------------- launch ----------------

extern "C" void kernel_launch(void* const* d_in, const int* in_sizes, int n_in,
                              void* d_out, int out_size, void* d_ws, size_t ws_size,
                              hipStream_t stream)
{
    const float* x   = (const float*)d_in[0];
    const int*   ei  = (const int*)d_in[1];
    const int*   bat = (const int*)d_in[2];
    const float* W1  = (const float*)d_in[3];
    const float* b1  = (const float*)d_in[4];
    const float* W2  = (const float*)d_in[5];
    const float* b2  = (const float*)d_in[6];
    const float* g1  = (const float*)d_in[7];
    const float* be1 = (const float*)d_in[8];
    const float* rm1 = (const float*)d_in[9];
    const float* rv1 = (const float*)d_in[10];
    const float* g2  = (const float*)d_in[11];
    const float* be2 = (const float*)d_in[12];
    const float* rm2 = (const float*)d_in[13];
    const float* rv2 = (const float*)d_in[14];
    float* outp = (float*)d_out;
    char* ws = (char*)d_ws;

    int*   bcnt    = (int*)  (ws + 0);         //     64 B (16 bucket counters)
    int*   offs    = (int*)  (ws + 200000);    // 200016 B (N+1 ints)
    float* dinv    = (float*)(ws + 400016);    // 200000 B
    float* inv_cnt = (float*)(ws + 600016);    //   8192 B
    int*   bsum    = (int*)  (ws + 608208);    //   1024 B
    int*   boff    = (int*)  (ws + 609232);    //   1024 B
    unsigned* csr  = (unsigned*)(ws + 610256);                  // 6.4 MB (u32 recs)
    unsigned short* Wbf1 = (unsigned short*)(ws + 7010256);     // 46080 B
    unsigned short* Wbf2 = (unsigned short*)(ws + 7056336);     // 46080 B
    unsigned short* Abf  = (unsigned short*)(ws + 7102416);     // 16015360 B (50048 x 160)
    unsigned short* Y1   = Abf;                                 // alias: Abf dead after gemm1
    unsigned short* Hb   = (unsigned short*)(ws + 23117776);    // 13613056 B (50048 x 136)
    // CSR-build scratch aliases Hb+ (dead before gemm1 writes Hb):
    unsigned* buckets = (unsigned*)(ws + 23117776);             // 7.04 MB
    int*      deg2    = (int*)    (ws + 30157776);              // 12.8 MB -> ends 42.96 MB

    hipMemsetAsync(bcnt, 0, 64, stream);
    hipMemsetAsync(d_out, 0, (size_t)out_size * 4, stream);

    const int* row = ei;
    const int* col = ei + N_EDGES;

    int nbl = (N_NODES + 255) / 256;

    k_part  <<<dim3(1024), dim3(256), 0, stream>>>(row, col, bcnt, buckets);
    k_prep  <<<dim3(X2BF_BLOCKS + 189), dim3(256), 0, stream>>>(x, (unsigned*)Abf,
                                                                W1, W2, Wbf1, Wbf2,
                                                                bat, inv_cnt);
    k_count2<<<dim3(NSLICE * NRANGE), dim3(256), 0, stream>>>(buckets, bcnt, deg2);
    k_scan1 <<<dim3(nbl), dim3(256), 0, stream>>>(deg2, dinv, offs, bsum);
    k_scan2 <<<dim3(1),   dim3(256), 0, stream>>>(bsum, boff, nbl);
    k_scan3C<<<dim3(nbl), dim3(256), 0, stream>>>(offs, boff, deg2);
    k_fill2 <<<dim3(NSLICE * NRANGE), dim3(256), 0, stream>>>(buckets, bcnt, deg2, dinv, csr);

    int gbl = N_ROWS / 64;   // 782
    k_gemm_mfma<<<dim3(gbl), dim3(256), 0, stream>>>(Abf, Wbf1, Hb, N_NODES);
    k_agg<false><<<dim3(N_NODES / 4), dim3(256), 0, stream>>>(Hb, offs, csr, dinv,
                                                              b1, g1, be1, rm1, rv1,
                                                              Y1, nullptr, nullptr, nullptr);
    k_gemm_mfma<<<dim3(gbl), dim3(256), 0, stream>>>(Y1, Wbf2, Hb, N_NODES);
    k_agg<true><<<dim3(N_NODES / 4), dim3(256), 0, stream>>>(Hb, offs, csr, dinv,
                                                             b2, g2, be2, rm2, rv2,
                                                             nullptr, bat, inv_cnt, outp);
}